// Round 17
// baseline (1661.633 us; speedup 1.0000x reference)
//
#include <hip/hip_runtime.h>
#include <hip/hip_fp16.h>

#define NU 100000
#define NI 50000
#define NE 819200
#define FIN 128
#define HH 32

#define NCH 200         // edge chunks of 4096
#define NBU 98          // user buckets of 1024 nodes
#define NBI 49          // item buckets of 1024 nodes

#define G_P0I 6250      // NI/8
#define G_P0U 12500     // NU/8
#define G_P1U 782       // ceil(NU/128)
#define G_P1I 391       // ceil(NI/128)

// ================= radix CSR build =================

__global__ void cnt1_k(const int4* __restrict__ eu4, const int4* __restrict__ ei4,
                       int* __restrict__ cntU, int* __restrict__ cntI) {
    __shared__ unsigned cnt[128];
    int b = blockIdx.x;
    int c, NB;
    const int4* D;
    int* M;
    if (b < NCH) { c = b; D = eu4; M = cntU; NB = NBU; }
    else         { c = b - NCH; D = ei4; M = cntI; NB = NBI; }
    int tid = threadIdx.x;
    if (tid < 128) cnt[tid] = 0u;
    __syncthreads();
    int base = c * 1024;
#pragma unroll
    for (int it = 0; it < 4; ++it) {
        int4 v = D[base + it * 256 + tid];
        atomicAdd(&cnt[v.x >> 10], 1u);
        atomicAdd(&cnt[v.y >> 10], 1u);
        atomicAdd(&cnt[v.z >> 10], 1u);
        atomicAdd(&cnt[v.w >> 10], 1u);
    }
    __syncthreads();
    for (int i = tid; i < NB; i += 256) M[i * NCH + c] = (int)cnt[i];
}

__global__ __launch_bounds__(1024) void scan2_k(int* __restrict__ aU, int nU,
                                                int* __restrict__ aI, int nI) {
    __shared__ int ts[1024];
    int t = threadIdx.x;
    for (int pass = 0; pass < 2; ++pass) {
        int* a = pass ? aI : aU;
        int n  = pass ? nI : nU;
        int nper = (n + 1023) / 1024;
        int beg = t * nper;
        int end = beg + nper; if (end > n) end = n;
        int s = 0;
        for (int i = beg; i < end; ++i) s += a[i];
        ts[t] = s;
        __syncthreads();
        int incl = s;
        for (int off = 1; off < 1024; off <<= 1) {
            int y = (t >= off) ? ts[t - off] : 0;
            __syncthreads();
            incl += y;
            ts[t] = incl;
            __syncthreads();
        }
        int run = incl - s;
        for (int i = beg; i < end; ++i) { int v = a[i]; a[i] = run; run += v; }
        __syncthreads();
    }
}

__global__ void part_k(const int4* __restrict__ eu4, const int4* __restrict__ ei4,
                       const int* __restrict__ cntU, const int* __restrict__ cntI,
                       int2* __restrict__ partU, int2* __restrict__ partI) {
    __shared__ unsigned cur[128];
    int b = blockIdx.x;
    int c, NB;
    const int4 *D, *P;
    const int* M;
    int2* out;
    if (b < NCH) { c = b; D = eu4; P = ei4; M = cntU; out = partU; NB = NBU; }
    else         { c = b - NCH; D = ei4; P = eu4; M = cntI; out = partI; NB = NBI; }
    int tid = threadIdx.x;
    for (int i = tid; i < NB; i += 256) cur[i] = (unsigned)M[i * NCH + c];
    __syncthreads();
    int base = c * 1024;
#pragma unroll
    for (int it = 0; it < 4; ++it) {
        int4 d = D[base + it * 256 + tid];
        int4 p = P[base + it * 256 + tid];
        unsigned s;
        s = atomicAdd(&cur[d.x >> 10], 1u); out[s] = make_int2(d.x, p.x);
        s = atomicAdd(&cur[d.y >> 10], 1u); out[s] = make_int2(d.y, p.y);
        s = atomicAdd(&cur[d.z >> 10], 1u); out[s] = make_int2(d.z, p.z);
        s = atomicAdd(&cur[d.w >> 10], 1u); out[s] = make_int2(d.w, p.w);
    }
}

__global__ __launch_bounds__(1024) void build_k(const int2* __restrict__ partU,
                                                const int2* __restrict__ partI,
                                                const int* __restrict__ cntU,
                                                const int* __restrict__ cntI,
                                                int* __restrict__ rsU, int* __restrict__ rsI,
                                                int* __restrict__ csrU, int* __restrict__ csrI) {
    __shared__ unsigned dcnt[1024];
    __shared__ unsigned sc_[1024];
    int b = blockIdx.x;
    const int2* part;
    const int* M;
    int *rs, *csr;
    int bi, N, NB;
    if (b < NBU) { bi = b; part = partU; M = cntU; rs = rsU; csr = csrU; N = NU; NB = NBU; }
    else         { bi = b - NBU; part = partI; M = cntI; rs = rsI; csr = csrI; N = NI; NB = NBI; }
    int lo = bi * 1024;
    int bktbase = M[bi * NCH];
    int bktend = (bi + 1 < NB) ? M[(bi + 1) * NCH] : NE;
    int t = threadIdx.x;
    dcnt[t] = 0u;
    __syncthreads();
    for (int j = bktbase + t; j < bktend; j += 1024) {
        int2 p = part[j];
        atomicAdd(&dcnt[p.x - lo], 1u);
    }
    __syncthreads();
    unsigned cme = dcnt[t];
    sc_[t] = cme;
    __syncthreads();
    unsigned incl = cme;
    for (int off = 1; off < 1024; off <<= 1) {
        unsigned y = (t >= off) ? sc_[t - off] : 0u;
        __syncthreads();
        incl += y;
        sc_[t] = incl;
        __syncthreads();
    }
    unsigned excl = incl - cme;
    if (lo + t < N) rs[lo + t] = bktbase + (int)excl;
    if (bi == NB - 1 && t == 0) rs[N] = NE;
    __syncthreads();
    dcnt[t] = excl;
    __syncthreads();
    for (int j = bktbase + t; j < bktend; j += 1024) {
        int2 p = part[j];
        unsigned s = atomicAdd(&dcnt[p.x - lo], 1u);
        csr[bktbase + (int)s] = p.y;
    }
}

// ======= proj128: W in LDS, X global->registers w/ prefetch, 512 thr / 128 nodes =======
__device__ __forceinline__ void proj128_body(const float* __restrict__ X,
                                             const float* __restrict__ Wl,
                                             const float* __restrict__ Wr,
                                             __half* __restrict__ S, float* __restrict__ R,
                                             int N, int vb, float* sW) {
    int tid = threadIdx.x;
#pragma unroll
    for (int it = 0; it < 4; ++it) {           // 2048 float4 = 64 cols x 128 k
        int idx = it * 512 + tid;
        int col = idx & 63, k = (idx >> 6) * 4;
        const float* src = (col < 32) ? (Wl + col * FIN + k) : (Wr + (col - 32) * FIN + k);
        float4 w = *(const float4*)src;
        sW[(k + 0) * 68 + col] = w.x;
        sW[(k + 1) * 68 + col] = w.y;
        sW[(k + 2) * 68 + col] = w.z;
        sW[(k + 3) * 68 + col] = w.w;
    }
    __syncthreads();
    int ct = tid & 15, nt = tid >> 4;          // nt in [0,32): 32 node-quads = 128 nodes
    int c0 = ct * 4;
    int n0 = vb * 128 + nt * 4;
    int mA = n0 + 0; if (mA >= N) mA = N - 1;
    int mB = n0 + 1; if (mB >= N) mB = N - 1;
    int mC = n0 + 2; if (mC >= N) mC = N - 1;
    int mD = n0 + 3; if (mD >= N) mD = N - 1;
    const float* xA = X + (size_t)mA * FIN;
    const float* xB = X + (size_t)mB * FIN;
    const float* xC = X + (size_t)mC * FIN;
    const float* xD = X + (size_t)mD * FIN;
    float acc[4][4];
#pragma unroll
    for (int j = 0; j < 4; ++j)
#pragma unroll
        for (int i = 0; i < 4; ++i) acc[j][i] = 0.f;
    float4 a4 = *(const float4*)(xA);
    float4 b4 = *(const float4*)(xB);
    float4 c4 = *(const float4*)(xC);
    float4 d4 = *(const float4*)(xD);
#pragma unroll
    for (int k4 = 0; k4 < FIN; k4 += 4) {
        float4 na, nb, nc, nd;
        if (k4 + 4 < FIN) {                    // static under full unroll
            na = *(const float4*)(xA + k4 + 4);
            nb = *(const float4*)(xB + k4 + 4);
            nc = *(const float4*)(xC + k4 + 4);
            nd = *(const float4*)(xD + k4 + 4);
        }
        float xa[4] = {a4.x, a4.y, a4.z, a4.w};
        float xb[4] = {b4.x, b4.y, b4.z, b4.w};
        float xc[4] = {c4.x, c4.y, c4.z, c4.w};
        float xd[4] = {d4.x, d4.y, d4.z, d4.w};
#pragma unroll
        for (int kk = 0; kk < 4; ++kk) {
            float4 w = *(const float4*)&sW[(k4 + kk) * 68 + c0];
            acc[0][0] += xa[kk] * w.x; acc[0][1] += xa[kk] * w.y;
            acc[0][2] += xa[kk] * w.z; acc[0][3] += xa[kk] * w.w;
            acc[1][0] += xb[kk] * w.x; acc[1][1] += xb[kk] * w.y;
            acc[1][2] += xb[kk] * w.z; acc[1][3] += xb[kk] * w.w;
            acc[2][0] += xc[kk] * w.x; acc[2][1] += xc[kk] * w.y;
            acc[2][2] += xc[kk] * w.z; acc[2][3] += xc[kk] * w.w;
            acc[3][0] += xd[kk] * w.x; acc[3][1] += xd[kk] * w.y;
            acc[3][2] += xd[kk] * w.z; acc[3][3] += xd[kk] * w.w;
        }
        if (k4 + 4 < FIN) { a4 = na; b4 = nb; c4 = nc; d4 = nd; }
    }
#pragma unroll
    for (int j = 0; j < 4; ++j) {
        int node = n0 + j;
        if (node < N) {
            if (c0 < 32) {
                __half2 h01 = __floats2half2_rn(acc[j][0], acc[j][1]);
                __half2 h23 = __floats2half2_rn(acc[j][2], acc[j][3]);
                __half2* dst = (__half2*)(S + (size_t)node * HH + c0);
                dst[0] = h01;
                dst[1] = h23;
            } else {
                float4 o;
                o.x = acc[j][0]; o.y = acc[j][1]; o.z = acc[j][2]; o.w = acc[j][3];
                *(float4*)(R + (size_t)node * HH + (c0 - 32)) = o;
            }
        }
    }
}

__global__ __launch_bounds__(512) void p1_k(const float* __restrict__ xu,
                                            const float* __restrict__ xi,
                                            const float* __restrict__ wl0_ui,
                                            const float* __restrict__ wr0_iu,
                                            const float* __restrict__ wl0_iu,
                                            const float* __restrict__ wr0_ui,
                                            __half* __restrict__ Su, float* __restrict__ Ru,
                                            __half* __restrict__ Si, float* __restrict__ Ri) {
    __shared__ float sW[128 * 68];
    int b = blockIdx.x;
    if (b < G_P1U) proj128_body(xu, wl0_ui, wr0_iu, Su, Ru, NU, b, sW);
    else           proj128_body(xi, wl0_iu, wr0_ui, Si, Ri, NI, b - G_P1U, sW);
}

// ==== gather: lane = (sc in [0,8): half4 chunk, eh in [0,4): edge slot) -> float4 acc ====
__device__ __forceinline__ float4 gather4(const int* __restrict__ csr, int s0, int s1,
                                          const __half* __restrict__ S, int sc, int eh) {
    const char* Sb = (const char*)S;
    float4 acc = {0.f, 0.f, 0.f, 0.f};
    int j = s0 + eh;
    for (; j + 4 < s1; j += 8) {
        int i0 = csr[j], i1 = csr[j + 4];
        uint2 u0 = *(const uint2*)(Sb + ((size_t)i0 << 6) + sc * 8);
        uint2 u1 = *(const uint2*)(Sb + ((size_t)i1 << 6) + sc * 8);
        float2 f00 = __half22float2(*(__half2*)&u0.x);
        float2 f01 = __half22float2(*(__half2*)&u0.y);
        float2 f10 = __half22float2(*(__half2*)&u1.x);
        float2 f11 = __half22float2(*(__half2*)&u1.y);
        acc.x += f00.x + f10.x;
        acc.y += f00.y + f10.y;
        acc.z += f01.x + f11.x;
        acc.w += f01.y + f11.y;
    }
    if (j < s1) {
        int i0 = csr[j];
        uint2 u0 = *(const uint2*)(Sb + ((size_t)i0 << 6) + sc * 8);
        float2 f00 = __half22float2(*(__half2*)&u0.x);
        float2 f01 = __half22float2(*(__half2*)&u0.y);
        acc.x += f00.x; acc.y += f00.y; acc.z += f01.x; acc.w += f01.y;
    }
    // reduce across edge slots (lane bits 3,4)
    acc.x += __shfl_xor(acc.x, 8);  acc.x += __shfl_xor(acc.x, 16);
    acc.y += __shfl_xor(acc.y, 8);  acc.y += __shfl_xor(acc.y, 16);
    acc.z += __shfl_xor(acc.z, 8);  acc.z += __shfl_xor(acc.z, 16);
    acc.w += __shfl_xor(acc.w, 8);  acc.w += __shfl_xor(acc.w, 16);
    return acc;
}

// ================= fused pull0 + proj32 (fp16 S in, fp16 S2 out) =================
__global__ void p23_k(const int* __restrict__ csrI, const int* __restrict__ rsI,
                      const __half* __restrict__ Su, float* __restrict__ Ri,
                      const float* __restrict__ b0_ui,
                      const float* __restrict__ wl1_iu, const float* __restrict__ wr1_ui,
                      __half* __restrict__ Si2,
                      const int* __restrict__ csrU, const int* __restrict__ rsU,
                      const __half* __restrict__ Si, float* __restrict__ Ru,
                      const float* __restrict__ b0_iu,
                      const float* __restrict__ wl1_ui, const float* __restrict__ wr1_iu,
                      __half* __restrict__ Su2) {
    __shared__ float sWl[HH * 36];
    __shared__ float sWr[HH * 36];
    __shared__ float sH[8][36];
    int b = blockIdx.x;
    const int *csr, *rs;
    const __half* S;
    const float *bias, *Wl, *Wr;
    float* Rb;
    __half* S2;
    int vb;
    if (b < G_P0I) {
        csr = csrI; rs = rsI; S = Su; Rb = Ri; bias = b0_ui;
        Wl = wl1_iu; Wr = wr1_ui; S2 = Si2; vb = b;
    } else {
        csr = csrU; rs = rsU; S = Si; Rb = Ru; bias = b0_iu;
        Wl = wl1_ui; Wr = wr1_iu; S2 = Su2; vb = b - G_P0I;
    }
    int tid = threadIdx.x;
    {
        float4 a = ((const float4*)Wl)[tid];
        float4 w = ((const float4*)Wr)[tid];
        int e0 = tid * 4;
        int o = e0 >> 5, k = e0 & 31;
        sWl[(k + 0) * 36 + o] = a.x;
        sWl[(k + 1) * 36 + o] = a.y;
        sWl[(k + 2) * 36 + o] = a.z;
        sWl[(k + 3) * 36 + o] = a.w;
        sWr[(k + 0) * 36 + o] = w.x;
        sWr[(k + 1) * 36 + o] = w.y;
        sWr[(k + 2) * 36 + o] = w.z;
        sWr[(k + 3) * 36 + o] = w.w;
    }
    int g = tid >> 5;
    int lane5 = tid & 31;
    int sc = lane5 & 7, eh = lane5 >> 3;
    int n = vb * 8 + g;
    int s0 = rs[n], s1 = rs[n + 1];
    float4 acc = gather4(csr, s0, s1, S, sc, eh);
    float deg = (float)(s1 - s0);
    deg = deg > 1.f ? deg : 1.f;
    float4 r4 = *(const float4*)(Rb + (size_t)n * HH + 4 * sc);
    float4 b4 = *(const float4*)(bias + 4 * sc);
    float4 v4;
    v4.x = acc.x / deg + r4.x + b4.x;
    v4.y = acc.y / deg + r4.y + b4.y;
    v4.z = acc.z / deg + r4.z + b4.z;
    v4.w = acc.w / deg + r4.w + b4.w;
    float ss = v4.x * v4.x + v4.y * v4.y + v4.z * v4.z + v4.w * v4.w;
    ss += __shfl_xor(ss, 1);
    ss += __shfl_xor(ss, 2);
    ss += __shfl_xor(ss, 4);
    float nrm = sqrtf(ss);
    nrm = nrm > 1e-12f ? nrm : 1e-12f;
    v4.x /= nrm; v4.y /= nrm; v4.z /= nrm; v4.w /= nrm;
    v4.x = v4.x > 0.f ? v4.x : 0.f;
    v4.y = v4.y > 0.f ? v4.y : 0.f;
    v4.z = v4.z > 0.f ? v4.z : 0.f;
    v4.w = v4.w > 0.f ? v4.w : 0.f;
    if (eh == 0) {
        sH[g][4 * sc + 0] = v4.x;
        sH[g][4 * sc + 1] = v4.y;
        sH[g][4 * sc + 2] = v4.z;
        sH[g][4 * sc + 3] = v4.w;
    }
    __syncthreads();
    int c = tid & 31;
    float aL = 0.f, aR = 0.f;
#pragma unroll
    for (int k = 0; k < HH; ++k) {
        float x = sH[g][k];
        aL += x * sWl[k * 36 + c];
        aR += x * sWr[k * 36 + c];
    }
    S2[(size_t)n * HH + c] = __float2half_rn(aL);
    Rb[(size_t)n * HH + c] = aR;
}

// ================= pull1 + final (fp16 S in) =================
__device__ __forceinline__ void pull1f_body(const int* __restrict__ csr,
                                            const int* __restrict__ rs,
                                            const __half* __restrict__ S,
                                            const float* __restrict__ R,
                                            const float* __restrict__ b1,
                                            const float* __restrict__ Wp,
                                            const float* __restrict__ bp,
                                            float* __restrict__ out, int vb, float* smem) {
    float* sWpT = smem;
    float* sH   = smem + HH * 36;
    int tid = threadIdx.x;
    {
        float4 a = ((const float4*)Wp)[tid];
        int e0 = tid * 4;
        int o = e0 >> 5, k = e0 & 31;
        sWpT[(k + 0) * 36 + o] = a.x;
        sWpT[(k + 1) * 36 + o] = a.y;
        sWpT[(k + 2) * 36 + o] = a.z;
        sWpT[(k + 3) * 36 + o] = a.w;
    }
    int g = tid >> 5;
    int lane5 = tid & 31;
    int sc = lane5 & 7, eh = lane5 >> 3;
    int n = vb * 8 + g;
    int s0 = rs[n], s1 = rs[n + 1];
    float4 acc = gather4(csr, s0, s1, S, sc, eh);
    float deg = (float)(s1 - s0);
    deg = deg > 1.f ? deg : 1.f;
    float4 r4 = *(const float4*)(R + (size_t)n * HH + 4 * sc);
    float4 b4 = *(const float4*)(b1 + 4 * sc);
    float4 v4;
    v4.x = acc.x / deg + r4.x + b4.x;
    v4.y = acc.y / deg + r4.y + b4.y;
    v4.z = acc.z / deg + r4.z + b4.z;
    v4.w = acc.w / deg + r4.w + b4.w;
    float ss = v4.x * v4.x + v4.y * v4.y + v4.z * v4.z + v4.w * v4.w;
    ss += __shfl_xor(ss, 1);
    ss += __shfl_xor(ss, 2);
    ss += __shfl_xor(ss, 4);
    float nrm = sqrtf(ss);
    nrm = nrm > 1e-12f ? nrm : 1e-12f;
    v4.x /= nrm; v4.y /= nrm; v4.z /= nrm; v4.w /= nrm;
    v4.x = v4.x > 0.f ? v4.x : 0.f;
    v4.y = v4.y > 0.f ? v4.y : 0.f;
    v4.z = v4.z > 0.f ? v4.z : 0.f;
    v4.w = v4.w > 0.f ? v4.w : 0.f;
    if (eh == 0) {
        sH[g * 36 + 4 * sc + 0] = v4.x;
        sH[g * 36 + 4 * sc + 1] = v4.y;
        sH[g * 36 + 4 * sc + 2] = v4.z;
        sH[g * 36 + 4 * sc + 3] = v4.w;
    }
    __syncthreads();
    int c = tid & 31;
    float a2f = bp[c];
#pragma unroll
    for (int k = 0; k < HH; ++k) a2f += sH[g * 36 + k] * sWpT[k * 36 + c];
    float s2 = a2f * a2f;
    s2 += __shfl_xor(s2, 1);
    s2 += __shfl_xor(s2, 2);
    s2 += __shfl_xor(s2, 4);
    s2 += __shfl_xor(s2, 8);
    s2 += __shfl_xor(s2, 16);
    float nrm2 = sqrtf(s2);
    nrm2 = nrm2 > 1e-12f ? nrm2 : 1e-12f;
    out[(size_t)n * HH + c] = a2f / nrm2;
}

__global__ void p4_k(const int* __restrict__ csrU, const int* __restrict__ rsU,
                     const __half* __restrict__ Si2, const float* __restrict__ Ru,
                     const float* __restrict__ b1_iu,
                     const float* __restrict__ wp_user, const float* __restrict__ bp_user,
                     const int* __restrict__ csrI, const int* __restrict__ rsI,
                     const __half* __restrict__ Su2, const float* __restrict__ Ri,
                     const float* __restrict__ b1_ui,
                     const float* __restrict__ wp_item, const float* __restrict__ bp_item,
                     float* __restrict__ out) {
    __shared__ float smem[HH * 36 + 8 * 36];
    int b = blockIdx.x;
    if (b < G_P0U) {
        pull1f_body(csrU, rsU, Si2, Ru, b1_iu, wp_user, bp_user, out, b, smem);
    } else {
        pull1f_body(csrI, rsI, Su2, Ri, b1_ui, wp_item, bp_item,
                    out + (size_t)NU * HH, b - G_P0U, smem);
    }
}

// ================= host =================

extern "C" void kernel_launch(void* const* d_in, const int* in_sizes, int n_in,
                              void* d_out, int out_size, void* d_ws, size_t ws_size,
                              hipStream_t stream) {
    const float* x_user = (const float*)d_in[0];
    const float* x_item = (const float*)d_in[1];
    const int* eu = (const int*)d_in[2];
    const int* ei = (const int*)d_in[3];
    const float* wl0_ui = (const float*)d_in[4];
    const float* b0_ui  = (const float*)d_in[5];
    const float* wr0_ui = (const float*)d_in[6];
    const float* wl0_iu = (const float*)d_in[7];
    const float* b0_iu  = (const float*)d_in[8];
    const float* wr0_iu = (const float*)d_in[9];
    const float* wl1_ui = (const float*)d_in[10];
    const float* b1_ui  = (const float*)d_in[11];
    const float* wr1_ui = (const float*)d_in[12];
    const float* wl1_iu = (const float*)d_in[13];
    const float* b1_iu  = (const float*)d_in[14];
    const float* wr1_iu = (const float*)d_in[15];
    const float* wp_user = (const float*)d_in[16];
    const float* bp_user = (const float*)d_in[17];
    const float* wp_item = (const float*)d_in[18];
    const float* bp_item = (const float*)d_in[19];
    float* out = (float*)d_out;
    (void)in_sizes; (void)n_in; (void)out_size; (void)ws_size;

    char* base = (char*)d_ws;
    size_t off = 0;
    auto take = [&](size_t bytes) -> size_t {
        size_t o = off;
        off += (bytes + 255) & ~(size_t)255;
        return o;
    };
    size_t o_rsU  = take((size_t)(NU + 1) * 4);
    size_t o_rsI  = take((size_t)(NI + 1) * 4);
    size_t o_cntU = take((size_t)NBU * NCH * 4);
    size_t o_cntI = take((size_t)NBI * NCH * 4);
    size_t o_csrU = take((size_t)NE * 4);
    size_t o_csrI = take((size_t)NE * 4);
    size_t o_partU = take((size_t)NE * 8);
    size_t o_partI = take((size_t)NE * 8);
    size_t o_Su = take((size_t)NU * HH * 2);   // fp16 message tables
    size_t o_Si = take((size_t)NI * HH * 2);
    size_t o_Su2 = take((size_t)NU * HH * 2);
    size_t o_Si2 = take((size_t)NI * HH * 2);
    size_t o_Ru = take((size_t)NU * HH * 4);   // f32 self tables
    size_t o_Ri = take((size_t)NI * HH * 4);

    int* rsU  = (int*)(base + o_rsU);
    int* rsI  = (int*)(base + o_rsI);
    int* cntU = (int*)(base + o_cntU);
    int* cntI = (int*)(base + o_cntI);
    int* csrU = (int*)(base + o_csrU);
    int* csrI = (int*)(base + o_csrI);
    int2* partU = (int2*)(base + o_partU);
    int2* partI = (int2*)(base + o_partI);
    __half* Su = (__half*)(base + o_Su);
    __half* Si = (__half*)(base + o_Si);
    __half* Su2 = (__half*)(base + o_Su2);
    __half* Si2 = (__half*)(base + o_Si2);
    float* Ru = (float*)(base + o_Ru);
    float* Ri = (float*)(base + o_Ri);

    // ---- radix CSR build (no global random atomics, no memset) ----
    cnt1_k<<<2 * NCH, 256, 0, stream>>>((const int4*)eu, (const int4*)ei, cntU, cntI);
    scan2_k<<<1, 1024, 0, stream>>>(cntU, NBU * NCH, cntI, NBI * NCH);
    part_k<<<2 * NCH, 256, 0, stream>>>((const int4*)eu, (const int4*)ei,
                                        cntU, cntI, partU, partI);
    build_k<<<NBU + NBI, 1024, 0, stream>>>(partU, partI, cntU, cntI,
                                            rsU, rsI, csrU, csrI);

    // ---- layer-0 projections (W-in-LDS, X->registers w/ prefetch, fp16 S) ----
    p1_k<<<G_P1U + G_P1I, 512, 0, stream>>>(x_user, x_item, wl0_ui, wr0_iu,
                                            wl0_iu, wr0_ui, Su, Ru, Si, Ri);

    // ---- layer-0 pulls fused with layer-1 projections ----
    p23_k<<<G_P0I + G_P0U, 256, 0, stream>>>(csrI, rsI, Su, Ri, b0_ui, wl1_iu, wr1_ui, Si2,
                                             csrU, rsU, Si, Ru, b0_iu, wl1_ui, wr1_iu, Su2);

    // ---- layer-1 pulls + final projections -> out ----
    p4_k<<<G_P0U + G_P0I, 256, 0, stream>>>(csrU, rsU, Si2, Ru, b1_iu, wp_user, bp_user,
                                            csrI, rsI, Su2, Ri, b1_ui, wp_item, bp_item,
                                            out);
}

// Round 18
// 223.077 us; speedup vs baseline: 7.4487x; 7.4487x over previous
//
#include <hip/hip_runtime.h>
#include <hip/hip_fp16.h>

#define NU 100000
#define NI 50000
#define NE 819200
#define FIN 128
#define HH 32

#define NCH 200         // edge chunks of 4096
#define NBU 98          // user buckets of 1024 nodes
#define NBI 49          // item buckets of 1024 nodes

#define G_P0I 6250      // NI/8
#define G_P0U 12500     // NU/8
#define G_P1U 782       // ceil(NU/128)
#define G_P1I 391       // ceil(NI/128)

// ================= radix CSR build =================

__global__ void cnt1_k(const int4* __restrict__ eu4, const int4* __restrict__ ei4,
                       int* __restrict__ cntU, int* __restrict__ cntI) {
    __shared__ unsigned cnt[128];
    int b = blockIdx.x;
    int c, NB;
    const int4* D;
    int* M;
    if (b < NCH) { c = b; D = eu4; M = cntU; NB = NBU; }
    else         { c = b - NCH; D = ei4; M = cntI; NB = NBI; }
    int tid = threadIdx.x;
    if (tid < 128) cnt[tid] = 0u;
    __syncthreads();
    int base = c * 1024;
#pragma unroll
    for (int it = 0; it < 4; ++it) {
        int4 v = D[base + it * 256 + tid];
        atomicAdd(&cnt[v.x >> 10], 1u);
        atomicAdd(&cnt[v.y >> 10], 1u);
        atomicAdd(&cnt[v.z >> 10], 1u);
        atomicAdd(&cnt[v.w >> 10], 1u);
    }
    __syncthreads();
    for (int i = tid; i < NB; i += 256) M[i * NCH + c] = (int)cnt[i];
}

__global__ __launch_bounds__(1024) void scan2_k(int* __restrict__ aU, int nU,
                                                int* __restrict__ aI, int nI) {
    __shared__ int ts[1024];
    int t = threadIdx.x;
    for (int pass = 0; pass < 2; ++pass) {
        int* a = pass ? aI : aU;
        int n  = pass ? nI : nU;
        int nper = (n + 1023) / 1024;
        int beg = t * nper;
        int end = beg + nper; if (end > n) end = n;
        int s = 0;
        for (int i = beg; i < end; ++i) s += a[i];
        ts[t] = s;
        __syncthreads();
        int incl = s;
        for (int off = 1; off < 1024; off <<= 1) {
            int y = (t >= off) ? ts[t - off] : 0;
            __syncthreads();
            incl += y;
            ts[t] = incl;
            __syncthreads();
        }
        int run = incl - s;
        for (int i = beg; i < end; ++i) { int v = a[i]; a[i] = run; run += v; }
        __syncthreads();
    }
}

__global__ void part_k(const int4* __restrict__ eu4, const int4* __restrict__ ei4,
                       const int* __restrict__ cntU, const int* __restrict__ cntI,
                       int2* __restrict__ partU, int2* __restrict__ partI) {
    __shared__ unsigned cur[128];
    int b = blockIdx.x;
    int c, NB;
    const int4 *D, *P;
    const int* M;
    int2* out;
    if (b < NCH) { c = b; D = eu4; P = ei4; M = cntU; out = partU; NB = NBU; }
    else         { c = b - NCH; D = ei4; P = eu4; M = cntI; out = partI; NB = NBI; }
    int tid = threadIdx.x;
    for (int i = tid; i < NB; i += 256) cur[i] = (unsigned)M[i * NCH + c];
    __syncthreads();
    int base = c * 1024;
#pragma unroll
    for (int it = 0; it < 4; ++it) {
        int4 d = D[base + it * 256 + tid];
        int4 p = P[base + it * 256 + tid];
        unsigned s;
        s = atomicAdd(&cur[d.x >> 10], 1u); out[s] = make_int2(d.x, p.x);
        s = atomicAdd(&cur[d.y >> 10], 1u); out[s] = make_int2(d.y, p.y);
        s = atomicAdd(&cur[d.z >> 10], 1u); out[s] = make_int2(d.z, p.z);
        s = atomicAdd(&cur[d.w >> 10], 1u); out[s] = make_int2(d.w, p.w);
    }
}

__global__ __launch_bounds__(1024) void build_k(const int2* __restrict__ partU,
                                                const int2* __restrict__ partI,
                                                const int* __restrict__ cntU,
                                                const int* __restrict__ cntI,
                                                int* __restrict__ rsU, int* __restrict__ rsI,
                                                int* __restrict__ csrU, int* __restrict__ csrI) {
    __shared__ unsigned dcnt[1024];
    __shared__ unsigned sc_[1024];
    int b = blockIdx.x;
    const int2* part;
    const int* M;
    int *rs, *csr;
    int bi, N, NB;
    if (b < NBU) { bi = b; part = partU; M = cntU; rs = rsU; csr = csrU; N = NU; NB = NBU; }
    else         { bi = b - NBU; part = partI; M = cntI; rs = rsI; csr = csrI; N = NI; NB = NBI; }
    int lo = bi * 1024;
    int bktbase = M[bi * NCH];
    int bktend = (bi + 1 < NB) ? M[(bi + 1) * NCH] : NE;
    int t = threadIdx.x;
    dcnt[t] = 0u;
    __syncthreads();
    for (int j = bktbase + t; j < bktend; j += 1024) {
        int2 p = part[j];
        atomicAdd(&dcnt[p.x - lo], 1u);
    }
    __syncthreads();
    unsigned cme = dcnt[t];
    sc_[t] = cme;
    __syncthreads();
    unsigned incl = cme;
    for (int off = 1; off < 1024; off <<= 1) {
        unsigned y = (t >= off) ? sc_[t - off] : 0u;
        __syncthreads();
        incl += y;
        sc_[t] = incl;
        __syncthreads();
    }
    unsigned excl = incl - cme;
    if (lo + t < N) rs[lo + t] = bktbase + (int)excl;
    if (bi == NB - 1 && t == 0) rs[N] = NE;
    __syncthreads();
    dcnt[t] = excl;
    __syncthreads();
    for (int j = bktbase + t; j < bktend; j += 1024) {
        int2 p = part[j];
        unsigned s = atomicAdd(&dcnt[p.x - lo], 1u);
        csr[bktbase + (int)s] = p.y;
    }
}

// ======= proj128: W in LDS, X global->registers, 512 threads / 128 nodes (round-16 body) =======
__device__ __forceinline__ void proj128_body(const float* __restrict__ X,
                                             const float* __restrict__ Wl,
                                             const float* __restrict__ Wr,
                                             __half* __restrict__ S, float* __restrict__ R,
                                             int N, int vb, float* sW) {
    int tid = threadIdx.x;
#pragma unroll
    for (int it = 0; it < 4; ++it) {           // 2048 float4 = 64 cols x 128 k
        int idx = it * 512 + tid;
        int col = idx & 63, k = (idx >> 6) * 4;
        const float* src = (col < 32) ? (Wl + col * FIN + k) : (Wr + (col - 32) * FIN + k);
        float4 w = *(const float4*)src;
        sW[(k + 0) * 68 + col] = w.x;
        sW[(k + 1) * 68 + col] = w.y;
        sW[(k + 2) * 68 + col] = w.z;
        sW[(k + 3) * 68 + col] = w.w;
    }
    __syncthreads();
    int ct = tid & 15, nt = tid >> 4;          // nt in [0,32): 32 node-quads = 128 nodes
    int c0 = ct * 4;
    int n0 = vb * 128 + nt * 4;
    int mA = n0 + 0; if (mA >= N) mA = N - 1;
    int mB = n0 + 1; if (mB >= N) mB = N - 1;
    int mC = n0 + 2; if (mC >= N) mC = N - 1;
    int mD = n0 + 3; if (mD >= N) mD = N - 1;
    const float* xA = X + (size_t)mA * FIN;
    const float* xB = X + (size_t)mB * FIN;
    const float* xC = X + (size_t)mC * FIN;
    const float* xD = X + (size_t)mD * FIN;
    float acc[4][4];
#pragma unroll
    for (int j = 0; j < 4; ++j)
#pragma unroll
        for (int i = 0; i < 4; ++i) acc[j][i] = 0.f;
#pragma unroll 4
    for (int k4 = 0; k4 < FIN; k4 += 4) {
        float4 a4 = *(const float4*)(xA + k4);
        float4 b4 = *(const float4*)(xB + k4);
        float4 c4 = *(const float4*)(xC + k4);
        float4 d4 = *(const float4*)(xD + k4);
        float xa[4] = {a4.x, a4.y, a4.z, a4.w};
        float xb[4] = {b4.x, b4.y, b4.z, b4.w};
        float xc[4] = {c4.x, c4.y, c4.z, c4.w};
        float xd[4] = {d4.x, d4.y, d4.z, d4.w};
#pragma unroll
        for (int kk = 0; kk < 4; ++kk) {
            float4 w = *(const float4*)&sW[(k4 + kk) * 68 + c0];
            acc[0][0] += xa[kk] * w.x; acc[0][1] += xa[kk] * w.y;
            acc[0][2] += xa[kk] * w.z; acc[0][3] += xa[kk] * w.w;
            acc[1][0] += xb[kk] * w.x; acc[1][1] += xb[kk] * w.y;
            acc[1][2] += xb[kk] * w.z; acc[1][3] += xb[kk] * w.w;
            acc[2][0] += xc[kk] * w.x; acc[2][1] += xc[kk] * w.y;
            acc[2][2] += xc[kk] * w.z; acc[2][3] += xc[kk] * w.w;
            acc[3][0] += xd[kk] * w.x; acc[3][1] += xd[kk] * w.y;
            acc[3][2] += xd[kk] * w.z; acc[3][3] += xd[kk] * w.w;
        }
    }
#pragma unroll
    for (int j = 0; j < 4; ++j) {
        int node = n0 + j;
        if (node < N) {
            if (c0 < 32) {
                __half2 h01 = __floats2half2_rn(acc[j][0], acc[j][1]);
                __half2 h23 = __floats2half2_rn(acc[j][2], acc[j][3]);
                __half2* dst = (__half2*)(S + (size_t)node * HH + c0);
                dst[0] = h01;
                dst[1] = h23;
            } else {
                float4 o;
                o.x = acc[j][0]; o.y = acc[j][1]; o.z = acc[j][2]; o.w = acc[j][3];
                *(float4*)(R + (size_t)node * HH + (c0 - 32)) = o;
            }
        }
    }
}

__global__ __launch_bounds__(512) void p1_k(const float* __restrict__ xu,
                                            const float* __restrict__ xi,
                                            const float* __restrict__ wl0_ui,
                                            const float* __restrict__ wr0_iu,
                                            const float* __restrict__ wl0_iu,
                                            const float* __restrict__ wr0_ui,
                                            __half* __restrict__ Su, float* __restrict__ Ru,
                                            __half* __restrict__ Si, float* __restrict__ Ri) {
    __shared__ float sW[128 * 68];
    int b = blockIdx.x;
    if (b < G_P1U) proj128_body(xu, wl0_ui, wr0_iu, Su, Ru, NU, b, sW);
    else           proj128_body(xi, wl0_iu, wr0_ui, Si, Ri, NI, b - G_P1U, sW);
}

// ==== gather: lane = (sc in [0,8): half4 chunk, eh in [0,4): edge slot) -> float4 acc ====
__device__ __forceinline__ float4 gather4(const int* __restrict__ csr, int s0, int s1,
                                          const __half* __restrict__ S, int sc, int eh) {
    const char* Sb = (const char*)S;
    float4 acc = {0.f, 0.f, 0.f, 0.f};
    int j = s0 + eh;
    for (; j + 4 < s1; j += 8) {
        int i0 = csr[j], i1 = csr[j + 4];
        uint2 u0 = *(const uint2*)(Sb + ((size_t)i0 << 6) + sc * 8);
        uint2 u1 = *(const uint2*)(Sb + ((size_t)i1 << 6) + sc * 8);
        float2 f00 = __half22float2(*(__half2*)&u0.x);
        float2 f01 = __half22float2(*(__half2*)&u0.y);
        float2 f10 = __half22float2(*(__half2*)&u1.x);
        float2 f11 = __half22float2(*(__half2*)&u1.y);
        acc.x += f00.x + f10.x;
        acc.y += f00.y + f10.y;
        acc.z += f01.x + f11.x;
        acc.w += f01.y + f11.y;
    }
    if (j < s1) {
        int i0 = csr[j];
        uint2 u0 = *(const uint2*)(Sb + ((size_t)i0 << 6) + sc * 8);
        float2 f00 = __half22float2(*(__half2*)&u0.x);
        float2 f01 = __half22float2(*(__half2*)&u0.y);
        acc.x += f00.x; acc.y += f00.y; acc.z += f01.x; acc.w += f01.y;
    }
    // reduce across edge slots (lane bits 3,4)
    acc.x += __shfl_xor(acc.x, 8);  acc.x += __shfl_xor(acc.x, 16);
    acc.y += __shfl_xor(acc.y, 8);  acc.y += __shfl_xor(acc.y, 16);
    acc.z += __shfl_xor(acc.z, 8);  acc.z += __shfl_xor(acc.z, 16);
    acc.w += __shfl_xor(acc.w, 8);  acc.w += __shfl_xor(acc.w, 16);
    return acc;
}

// ================= fused pull0 + proj32 (fp16 S in, fp16 S2 out) =================
__global__ void p23_k(const int* __restrict__ csrI, const int* __restrict__ rsI,
                      const __half* __restrict__ Su, float* __restrict__ Ri,
                      const float* __restrict__ b0_ui,
                      const float* __restrict__ wl1_iu, const float* __restrict__ wr1_ui,
                      __half* __restrict__ Si2,
                      const int* __restrict__ csrU, const int* __restrict__ rsU,
                      const __half* __restrict__ Si, float* __restrict__ Ru,
                      const float* __restrict__ b0_iu,
                      const float* __restrict__ wl1_ui, const float* __restrict__ wr1_iu,
                      __half* __restrict__ Su2) {
    __shared__ float sWl[HH * 36];
    __shared__ float sWr[HH * 36];
    __shared__ float sH[8][36];
    int b = blockIdx.x;
    const int *csr, *rs;
    const __half* S;
    const float *bias, *Wl, *Wr;
    float* Rb;
    __half* S2;
    int vb;
    if (b < G_P0I) {
        csr = csrI; rs = rsI; S = Su; Rb = Ri; bias = b0_ui;
        Wl = wl1_iu; Wr = wr1_ui; S2 = Si2; vb = b;
    } else {
        csr = csrU; rs = rsU; S = Si; Rb = Ru; bias = b0_iu;
        Wl = wl1_ui; Wr = wr1_iu; S2 = Su2; vb = b - G_P0I;
    }
    int tid = threadIdx.x;
    {
        float4 a = ((const float4*)Wl)[tid];
        float4 w = ((const float4*)Wr)[tid];
        int e0 = tid * 4;
        int o = e0 >> 5, k = e0 & 31;
        sWl[(k + 0) * 36 + o] = a.x;
        sWl[(k + 1) * 36 + o] = a.y;
        sWl[(k + 2) * 36 + o] = a.z;
        sWl[(k + 3) * 36 + o] = a.w;
        sWr[(k + 0) * 36 + o] = w.x;
        sWr[(k + 1) * 36 + o] = w.y;
        sWr[(k + 2) * 36 + o] = w.z;
        sWr[(k + 3) * 36 + o] = w.w;
    }
    int g = tid >> 5;
    int lane5 = tid & 31;
    int sc = lane5 & 7, eh = lane5 >> 3;
    int n = vb * 8 + g;
    int s0 = rs[n], s1 = rs[n + 1];
    float4 acc = gather4(csr, s0, s1, S, sc, eh);
    float deg = (float)(s1 - s0);
    deg = deg > 1.f ? deg : 1.f;
    float4 r4 = *(const float4*)(Rb + (size_t)n * HH + 4 * sc);
    float4 b4 = *(const float4*)(bias + 4 * sc);
    float4 v4;
    v4.x = acc.x / deg + r4.x + b4.x;
    v4.y = acc.y / deg + r4.y + b4.y;
    v4.z = acc.z / deg + r4.z + b4.z;
    v4.w = acc.w / deg + r4.w + b4.w;
    float ss = v4.x * v4.x + v4.y * v4.y + v4.z * v4.z + v4.w * v4.w;
    ss += __shfl_xor(ss, 1);
    ss += __shfl_xor(ss, 2);
    ss += __shfl_xor(ss, 4);
    float nrm = sqrtf(ss);
    nrm = nrm > 1e-12f ? nrm : 1e-12f;
    v4.x /= nrm; v4.y /= nrm; v4.z /= nrm; v4.w /= nrm;
    v4.x = v4.x > 0.f ? v4.x : 0.f;
    v4.y = v4.y > 0.f ? v4.y : 0.f;
    v4.z = v4.z > 0.f ? v4.z : 0.f;
    v4.w = v4.w > 0.f ? v4.w : 0.f;
    if (eh == 0) {
        sH[g][4 * sc + 0] = v4.x;
        sH[g][4 * sc + 1] = v4.y;
        sH[g][4 * sc + 2] = v4.z;
        sH[g][4 * sc + 3] = v4.w;
    }
    __syncthreads();
    int c = tid & 31;
    float aL = 0.f, aR = 0.f;
#pragma unroll
    for (int k = 0; k < HH; ++k) {
        float x = sH[g][k];
        aL += x * sWl[k * 36 + c];
        aR += x * sWr[k * 36 + c];
    }
    S2[(size_t)n * HH + c] = __float2half_rn(aL);
    Rb[(size_t)n * HH + c] = aR;
}

// ================= pull1 + final (fp16 S in) =================
__device__ __forceinline__ void pull1f_body(const int* __restrict__ csr,
                                            const int* __restrict__ rs,
                                            const __half* __restrict__ S,
                                            const float* __restrict__ R,
                                            const float* __restrict__ b1,
                                            const float* __restrict__ Wp,
                                            const float* __restrict__ bp,
                                            float* __restrict__ out, int vb, float* smem) {
    float* sWpT = smem;
    float* sH   = smem + HH * 36;
    int tid = threadIdx.x;
    {
        float4 a = ((const float4*)Wp)[tid];
        int e0 = tid * 4;
        int o = e0 >> 5, k = e0 & 31;
        sWpT[(k + 0) * 36 + o] = a.x;
        sWpT[(k + 1) * 36 + o] = a.y;
        sWpT[(k + 2) * 36 + o] = a.z;
        sWpT[(k + 3) * 36 + o] = a.w;
    }
    int g = tid >> 5;
    int lane5 = tid & 31;
    int sc = lane5 & 7, eh = lane5 >> 3;
    int n = vb * 8 + g;
    int s0 = rs[n], s1 = rs[n + 1];
    float4 acc = gather4(csr, s0, s1, S, sc, eh);
    float deg = (float)(s1 - s0);
    deg = deg > 1.f ? deg : 1.f;
    float4 r4 = *(const float4*)(R + (size_t)n * HH + 4 * sc);
    float4 b4 = *(const float4*)(b1 + 4 * sc);
    float4 v4;
    v4.x = acc.x / deg + r4.x + b4.x;
    v4.y = acc.y / deg + r4.y + b4.y;
    v4.z = acc.z / deg + r4.z + b4.z;
    v4.w = acc.w / deg + r4.w + b4.w;
    float ss = v4.x * v4.x + v4.y * v4.y + v4.z * v4.z + v4.w * v4.w;
    ss += __shfl_xor(ss, 1);
    ss += __shfl_xor(ss, 2);
    ss += __shfl_xor(ss, 4);
    float nrm = sqrtf(ss);
    nrm = nrm > 1e-12f ? nrm : 1e-12f;
    v4.x /= nrm; v4.y /= nrm; v4.z /= nrm; v4.w /= nrm;
    v4.x = v4.x > 0.f ? v4.x : 0.f;
    v4.y = v4.y > 0.f ? v4.y : 0.f;
    v4.z = v4.z > 0.f ? v4.z : 0.f;
    v4.w = v4.w > 0.f ? v4.w : 0.f;
    if (eh == 0) {
        sH[g * 36 + 4 * sc + 0] = v4.x;
        sH[g * 36 + 4 * sc + 1] = v4.y;
        sH[g * 36 + 4 * sc + 2] = v4.z;
        sH[g * 36 + 4 * sc + 3] = v4.w;
    }
    __syncthreads();
    int c = tid & 31;
    float a2f = bp[c];
#pragma unroll
    for (int k = 0; k < HH; ++k) a2f += sH[g * 36 + k] * sWpT[k * 36 + c];
    float s2 = a2f * a2f;
    s2 += __shfl_xor(s2, 1);
    s2 += __shfl_xor(s2, 2);
    s2 += __shfl_xor(s2, 4);
    s2 += __shfl_xor(s2, 8);
    s2 += __shfl_xor(s2, 16);
    float nrm2 = sqrtf(s2);
    nrm2 = nrm2 > 1e-12f ? nrm2 : 1e-12f;
    out[(size_t)n * HH + c] = a2f / nrm2;
}

__global__ void p4_k(const int* __restrict__ csrU, const int* __restrict__ rsU,
                     const __half* __restrict__ Si2, const float* __restrict__ Ru,
                     const float* __restrict__ b1_iu,
                     const float* __restrict__ wp_user, const float* __restrict__ bp_user,
                     const int* __restrict__ csrI, const int* __restrict__ rsI,
                     const __half* __restrict__ Su2, const float* __restrict__ Ri,
                     const float* __restrict__ b1_ui,
                     const float* __restrict__ wp_item, const float* __restrict__ bp_item,
                     float* __restrict__ out) {
    __shared__ float smem[HH * 36 + 8 * 36];
    int b = blockIdx.x;
    if (b < G_P0U) {
        pull1f_body(csrU, rsU, Si2, Ru, b1_iu, wp_user, bp_user, out, b, smem);
    } else {
        pull1f_body(csrI, rsI, Su2, Ri, b1_ui, wp_item, bp_item,
                    out + (size_t)NU * HH, b - G_P0U, smem);
    }
}

// ================= host =================

extern "C" void kernel_launch(void* const* d_in, const int* in_sizes, int n_in,
                              void* d_out, int out_size, void* d_ws, size_t ws_size,
                              hipStream_t stream) {
    const float* x_user = (const float*)d_in[0];
    const float* x_item = (const float*)d_in[1];
    const int* eu = (const int*)d_in[2];
    const int* ei = (const int*)d_in[3];
    const float* wl0_ui = (const float*)d_in[4];
    const float* b0_ui  = (const float*)d_in[5];
    const float* wr0_ui = (const float*)d_in[6];
    const float* wl0_iu = (const float*)d_in[7];
    const float* b0_iu  = (const float*)d_in[8];
    const float* wr0_iu = (const float*)d_in[9];
    const float* wl1_ui = (const float*)d_in[10];
    const float* b1_ui  = (const float*)d_in[11];
    const float* wr1_ui = (const float*)d_in[12];
    const float* wl1_iu = (const float*)d_in[13];
    const float* b1_iu  = (const float*)d_in[14];
    const float* wr1_iu = (const float*)d_in[15];
    const float* wp_user = (const float*)d_in[16];
    const float* bp_user = (const float*)d_in[17];
    const float* wp_item = (const float*)d_in[18];
    const float* bp_item = (const float*)d_in[19];
    float* out = (float*)d_out;
    (void)in_sizes; (void)n_in; (void)out_size; (void)ws_size;

    char* base = (char*)d_ws;
    size_t off = 0;
    auto take = [&](size_t bytes) -> size_t {
        size_t o = off;
        off += (bytes + 255) & ~(size_t)255;
        return o;
    };
    size_t o_rsU  = take((size_t)(NU + 1) * 4);
    size_t o_rsI  = take((size_t)(NI + 1) * 4);
    size_t o_cntU = take((size_t)NBU * NCH * 4);
    size_t o_cntI = take((size_t)NBI * NCH * 4);
    size_t o_csrU = take((size_t)NE * 4);
    size_t o_csrI = take((size_t)NE * 4);
    size_t o_partU = take((size_t)NE * 8);
    size_t o_partI = take((size_t)NE * 8);
    size_t o_Su = take((size_t)NU * HH * 2);   // fp16 message tables
    size_t o_Si = take((size_t)NI * HH * 2);
    size_t o_Su2 = take((size_t)NU * HH * 2);
    size_t o_Si2 = take((size_t)NI * HH * 2);
    size_t o_Ru = take((size_t)NU * HH * 4);   // f32 self tables
    size_t o_Ri = take((size_t)NI * HH * 4);

    int* rsU  = (int*)(base + o_rsU);
    int* rsI  = (int*)(base + o_rsI);
    int* cntU = (int*)(base + o_cntU);
    int* cntI = (int*)(base + o_cntI);
    int* csrU = (int*)(base + o_csrU);
    int* csrI = (int*)(base + o_csrI);
    int2* partU = (int2*)(base + o_partU);
    int2* partI = (int2*)(base + o_partI);
    __half* Su = (__half*)(base + o_Su);
    __half* Si = (__half*)(base + o_Si);
    __half* Su2 = (__half*)(base + o_Su2);
    __half* Si2 = (__half*)(base + o_Si2);
    float* Ru = (float*)(base + o_Ru);
    float* Ri = (float*)(base + o_Ri);

    // ---- radix CSR build (no global random atomics, no memset) ----
    cnt1_k<<<2 * NCH, 256, 0, stream>>>((const int4*)eu, (const int4*)ei, cntU, cntI);
    scan2_k<<<1, 1024, 0, stream>>>(cntU, NBU * NCH, cntI, NBI * NCH);
    part_k<<<2 * NCH, 256, 0, stream>>>((const int4*)eu, (const int4*)ei,
                                        cntU, cntI, partU, partI);
    build_k<<<NBU + NBI, 1024, 0, stream>>>(partU, partI, cntU, cntI,
                                            rsU, rsI, csrU, csrI);

    // ---- layer-0 projections (W-in-LDS, X->registers, fp16 S) ----
    p1_k<<<G_P1U + G_P1I, 512, 0, stream>>>(x_user, x_item, wl0_ui, wr0_iu,
                                            wl0_iu, wr0_ui, Su, Ru, Si, Ri);

    // ---- layer-0 pulls fused with layer-1 projections ----
    p23_k<<<G_P0I + G_P0U, 256, 0, stream>>>(csrI, rsI, Su, Ri, b0_ui, wl1_iu, wr1_ui, Si2,
                                             csrU, rsU, Si, Ru, b0_iu, wl1_ui, wr1_iu, Su2);

    // ---- layer-1 pulls + final projections -> out ----
    p4_k<<<G_P0U + G_P0I, 256, 0, stream>>>(csrU, rsU, Si2, Ru, b1_iu, wp_user, bp_user,
                                            csrI, rsI, Su2, Ri, b1_ui, wp_item, bp_item,
                                            out);
}

// Round 19
// 199.878 us; speedup vs baseline: 8.3132x; 1.1161x over previous
//
#include <hip/hip_runtime.h>
#include <hip/hip_fp16.h>

#define NU 100000
#define NI 50000
#define NE 819200
#define FIN 128
#define HH 32

#define NCH 200         // edge chunks of 4096
#define NBU 98          // user buckets of 1024 nodes
#define NBI 49          // item buckets of 1024 nodes

#define G_P0I 6250      // NI/8
#define G_P0U 12500     // NU/8
#define GPU_B 640       // user proj blocks
#define GPI_B 320       // item proj blocks

typedef _Float16 f16x8 __attribute__((ext_vector_type(8)));
typedef float f32x4 __attribute__((ext_vector_type(4)));

// ================= radix CSR build =================

__global__ void cnt1_k(const int4* __restrict__ eu4, const int4* __restrict__ ei4,
                       int* __restrict__ cntU, int* __restrict__ cntI) {
    __shared__ unsigned cnt[128];
    int b = blockIdx.x;
    int c, NB;
    const int4* D;
    int* M;
    if (b < NCH) { c = b; D = eu4; M = cntU; NB = NBU; }
    else         { c = b - NCH; D = ei4; M = cntI; NB = NBI; }
    int tid = threadIdx.x;
    if (tid < 128) cnt[tid] = 0u;
    __syncthreads();
    int base = c * 1024;
#pragma unroll
    for (int it = 0; it < 4; ++it) {
        int4 v = D[base + it * 256 + tid];
        atomicAdd(&cnt[v.x >> 10], 1u);
        atomicAdd(&cnt[v.y >> 10], 1u);
        atomicAdd(&cnt[v.z >> 10], 1u);
        atomicAdd(&cnt[v.w >> 10], 1u);
    }
    __syncthreads();
    for (int i = tid; i < NB; i += 256) M[i * NCH + c] = (int)cnt[i];
}

__global__ __launch_bounds__(1024) void scan2_k(int* __restrict__ aU, int nU,
                                                int* __restrict__ aI, int nI) {
    __shared__ int ts[1024];
    int t = threadIdx.x;
    for (int pass = 0; pass < 2; ++pass) {
        int* a = pass ? aI : aU;
        int n  = pass ? nI : nU;
        int nper = (n + 1023) / 1024;
        int beg = t * nper;
        int end = beg + nper; if (end > n) end = n;
        int s = 0;
        for (int i = beg; i < end; ++i) s += a[i];
        ts[t] = s;
        __syncthreads();
        int incl = s;
        for (int off = 1; off < 1024; off <<= 1) {
            int y = (t >= off) ? ts[t - off] : 0;
            __syncthreads();
            incl += y;
            ts[t] = incl;
            __syncthreads();
        }
        int run = incl - s;
        for (int i = beg; i < end; ++i) { int v = a[i]; a[i] = run; run += v; }
        __syncthreads();
    }
}

__global__ void part_k(const int4* __restrict__ eu4, const int4* __restrict__ ei4,
                       const int* __restrict__ cntU, const int* __restrict__ cntI,
                       int2* __restrict__ partU, int2* __restrict__ partI) {
    __shared__ unsigned cur[128];
    int b = blockIdx.x;
    int c, NB;
    const int4 *D, *P;
    const int* M;
    int2* out;
    if (b < NCH) { c = b; D = eu4; P = ei4; M = cntU; out = partU; NB = NBU; }
    else         { c = b - NCH; D = ei4; P = eu4; M = cntI; out = partI; NB = NBI; }
    int tid = threadIdx.x;
    for (int i = tid; i < NB; i += 256) cur[i] = (unsigned)M[i * NCH + c];
    __syncthreads();
    int base = c * 1024;
#pragma unroll
    for (int it = 0; it < 4; ++it) {
        int4 d = D[base + it * 256 + tid];
        int4 p = P[base + it * 256 + tid];
        unsigned s;
        s = atomicAdd(&cur[d.x >> 10], 1u); out[s] = make_int2(d.x, p.x);
        s = atomicAdd(&cur[d.y >> 10], 1u); out[s] = make_int2(d.y, p.y);
        s = atomicAdd(&cur[d.z >> 10], 1u); out[s] = make_int2(d.z, p.z);
        s = atomicAdd(&cur[d.w >> 10], 1u); out[s] = make_int2(d.w, p.w);
    }
}

__global__ __launch_bounds__(1024) void build_k(const int2* __restrict__ partU,
                                                const int2* __restrict__ partI,
                                                const int* __restrict__ cntU,
                                                const int* __restrict__ cntI,
                                                int* __restrict__ rsU, int* __restrict__ rsI,
                                                int* __restrict__ csrU, int* __restrict__ csrI) {
    __shared__ unsigned dcnt[1024];
    __shared__ unsigned sc_[1024];
    int b = blockIdx.x;
    const int2* part;
    const int* M;
    int *rs, *csr;
    int bi, N, NB;
    if (b < NBU) { bi = b; part = partU; M = cntU; rs = rsU; csr = csrU; N = NU; NB = NBU; }
    else         { bi = b - NBU; part = partI; M = cntI; rs = rsI; csr = csrI; N = NI; NB = NBI; }
    int lo = bi * 1024;
    int bktbase = M[bi * NCH];
    int bktend = (bi + 1 < NB) ? M[(bi + 1) * NCH] : NE;
    int t = threadIdx.x;
    dcnt[t] = 0u;
    __syncthreads();
    for (int j = bktbase + t; j < bktend; j += 1024) {
        int2 p = part[j];
        atomicAdd(&dcnt[p.x - lo], 1u);
    }
    __syncthreads();
    unsigned cme = dcnt[t];
    sc_[t] = cme;
    __syncthreads();
    unsigned incl = cme;
    for (int off = 1; off < 1024; off <<= 1) {
        unsigned y = (t >= off) ? sc_[t - off] : 0u;
        __syncthreads();
        incl += y;
        sc_[t] = incl;
        __syncthreads();
    }
    unsigned excl = incl - cme;
    if (lo + t < N) rs[lo + t] = bktbase + (int)excl;
    if (bi == NB - 1 && t == 0) rs[N] = NE;
    __syncthreads();
    dcnt[t] = excl;
    __syncthreads();
    for (int j = bktbase + t; j < bktend; j += 1024) {
        int2 p = part[j];
        unsigned s = atomicAdd(&dcnt[p.x - lo], 1u);
        csr[bktbase + (int)s] = p.y;
    }
}

// ======= proj128 via MFMA: per wave 16 nodes x 64 cols, B-frags in registers =======
__global__ __launch_bounds__(256) void p1m_k(const float* __restrict__ xu,
                                             const float* __restrict__ xi,
                                             const float* __restrict__ wl0_ui,
                                             const float* __restrict__ wr0_iu,
                                             const float* __restrict__ wl0_iu,
                                             const float* __restrict__ wr0_ui,
                                             __half* __restrict__ Su, float* __restrict__ Ru,
                                             __half* __restrict__ Si, float* __restrict__ Ri) {
    const float *X, *Wl, *Wr;
    __half* S;
    float* R;
    int N, nwv, wid;
    int b = blockIdx.x;
    if (b < GPU_B) {
        X = xu; Wl = wl0_ui; Wr = wr0_iu; S = Su; R = Ru; N = NU;
        nwv = GPU_B * 4; wid = b * 4 + (threadIdx.x >> 6);
    } else {
        int bb = b - GPU_B;
        X = xi; Wl = wl0_iu; Wr = wr0_ui; S = Si; R = Ri; N = NI;
        nwv = GPI_B * 4; wid = bb * 4 + (threadIdx.x >> 6);
    }
    int lane = threadIdx.x & 63;
    int l15 = lane & 15, kq = lane >> 4;
    // B fragments: B[k][col], col = nt*16 + l15, k = ks*32 + kq*8 + j
    f16x8 bf[4][4];
#pragma unroll
    for (int nt = 0; nt < 4; ++nt) {
        int col = nt * 16 + l15;
        const float* wrow = (col < 32) ? (Wl + (size_t)col * FIN)
                                       : (Wr + (size_t)(col - 32) * FIN);
#pragma unroll
        for (int ks = 0; ks < 4; ++ks) {
            int k0 = ks * 32 + kq * 8;
            float4 wa = *(const float4*)(wrow + k0);
            float4 wb = *(const float4*)(wrow + k0 + 4);
            f16x8 v;
            v[0] = (_Float16)wa.x; v[1] = (_Float16)wa.y;
            v[2] = (_Float16)wa.z; v[3] = (_Float16)wa.w;
            v[4] = (_Float16)wb.x; v[5] = (_Float16)wb.y;
            v[6] = (_Float16)wb.z; v[7] = (_Float16)wb.w;
            bf[ks][nt] = v;
        }
    }
    int tiles = (N + 15) >> 4;
    for (int t = wid; t < tiles; t += nwv) {
        int row = t * 16 + l15;
        if (row >= N) row = N - 1;
        const float* xrow = X + (size_t)row * FIN;
        f32x4 a0 = {0.f, 0.f, 0.f, 0.f};
        f32x4 a1 = {0.f, 0.f, 0.f, 0.f};
        f32x4 a2 = {0.f, 0.f, 0.f, 0.f};
        f32x4 a3 = {0.f, 0.f, 0.f, 0.f};
#pragma unroll
        for (int ks = 0; ks < 4; ++ks) {
            int k0 = ks * 32 + kq * 8;
            float4 xa = *(const float4*)(xrow + k0);
            float4 xb = *(const float4*)(xrow + k0 + 4);
            f16x8 af;
            af[0] = (_Float16)xa.x; af[1] = (_Float16)xa.y;
            af[2] = (_Float16)xa.z; af[3] = (_Float16)xa.w;
            af[4] = (_Float16)xb.x; af[5] = (_Float16)xb.y;
            af[6] = (_Float16)xb.z; af[7] = (_Float16)xb.w;
            a0 = __builtin_amdgcn_mfma_f32_16x16x32_f16(af, bf[ks][0], a0, 0, 0, 0);
            a1 = __builtin_amdgcn_mfma_f32_16x16x32_f16(af, bf[ks][1], a1, 0, 0, 0);
            a2 = __builtin_amdgcn_mfma_f32_16x16x32_f16(af, bf[ks][2], a2, 0, 0, 0);
            a3 = __builtin_amdgcn_mfma_f32_16x16x32_f16(af, bf[ks][3], a3, 0, 0, 0);
        }
        int rbase = t * 16 + kq * 4;
#pragma unroll
        for (int r = 0; r < 4; ++r) {
            int node = rbase + r;
            if (node < N) {
                _Float16* srow = (_Float16*)(S + (size_t)node * HH);
                srow[l15]      = (_Float16)a0[r];
                srow[16 + l15] = (_Float16)a1[r];
                float* rrow = R + (size_t)node * HH;
                rrow[l15]      = a2[r];
                rrow[16 + l15] = a3[r];
            }
        }
    }
}

// ==== gather: lane = (sc in [0,8): half4 chunk, eh in [0,4): edge slot) -> float4 acc ====
__device__ __forceinline__ float4 gather4(const int* __restrict__ csr, int s0, int s1,
                                          const __half* __restrict__ S, int sc, int eh) {
    const char* Sb = (const char*)S;
    float4 acc = {0.f, 0.f, 0.f, 0.f};
    int j = s0 + eh;
    for (; j + 4 < s1; j += 8) {
        int i0 = csr[j], i1 = csr[j + 4];
        uint2 u0 = *(const uint2*)(Sb + ((size_t)i0 << 6) + sc * 8);
        uint2 u1 = *(const uint2*)(Sb + ((size_t)i1 << 6) + sc * 8);
        float2 f00 = __half22float2(*(__half2*)&u0.x);
        float2 f01 = __half22float2(*(__half2*)&u0.y);
        float2 f10 = __half22float2(*(__half2*)&u1.x);
        float2 f11 = __half22float2(*(__half2*)&u1.y);
        acc.x += f00.x + f10.x;
        acc.y += f00.y + f10.y;
        acc.z += f01.x + f11.x;
        acc.w += f01.y + f11.y;
    }
    if (j < s1) {
        int i0 = csr[j];
        uint2 u0 = *(const uint2*)(Sb + ((size_t)i0 << 6) + sc * 8);
        float2 f00 = __half22float2(*(__half2*)&u0.x);
        float2 f01 = __half22float2(*(__half2*)&u0.y);
        acc.x += f00.x; acc.y += f00.y; acc.z += f01.x; acc.w += f01.y;
    }
    acc.x += __shfl_xor(acc.x, 8);  acc.x += __shfl_xor(acc.x, 16);
    acc.y += __shfl_xor(acc.y, 8);  acc.y += __shfl_xor(acc.y, 16);
    acc.z += __shfl_xor(acc.z, 8);  acc.z += __shfl_xor(acc.z, 16);
    acc.w += __shfl_xor(acc.w, 8);  acc.w += __shfl_xor(acc.w, 16);
    return acc;
}

// ================= fused pull0 + proj32 (fp16 S in, fp16 S2 out) =================
__global__ void p23_k(const int* __restrict__ csrI, const int* __restrict__ rsI,
                      const __half* __restrict__ Su, float* __restrict__ Ri,
                      const float* __restrict__ b0_ui,
                      const float* __restrict__ wl1_iu, const float* __restrict__ wr1_ui,
                      __half* __restrict__ Si2,
                      const int* __restrict__ csrU, const int* __restrict__ rsU,
                      const __half* __restrict__ Si, float* __restrict__ Ru,
                      const float* __restrict__ b0_iu,
                      const float* __restrict__ wl1_ui, const float* __restrict__ wr1_iu,
                      __half* __restrict__ Su2) {
    __shared__ float sWl[HH * 36];
    __shared__ float sWr[HH * 36];
    __shared__ float sH[8][36];
    int b = blockIdx.x;
    const int *csr, *rs;
    const __half* S;
    const float *bias, *Wl, *Wr;
    float* Rb;
    __half* S2;
    int vb;
    if (b < G_P0I) {
        csr = csrI; rs = rsI; S = Su; Rb = Ri; bias = b0_ui;
        Wl = wl1_iu; Wr = wr1_ui; S2 = Si2; vb = b;
    } else {
        csr = csrU; rs = rsU; S = Si; Rb = Ru; bias = b0_iu;
        Wl = wl1_ui; Wr = wr1_iu; S2 = Su2; vb = b - G_P0I;
    }
    int tid = threadIdx.x;
    {
        float4 a = ((const float4*)Wl)[tid];
        float4 w = ((const float4*)Wr)[tid];
        int e0 = tid * 4;
        int o = e0 >> 5, k = e0 & 31;
        sWl[(k + 0) * 36 + o] = a.x;
        sWl[(k + 1) * 36 + o] = a.y;
        sWl[(k + 2) * 36 + o] = a.z;
        sWl[(k + 3) * 36 + o] = a.w;
        sWr[(k + 0) * 36 + o] = w.x;
        sWr[(k + 1) * 36 + o] = w.y;
        sWr[(k + 2) * 36 + o] = w.z;
        sWr[(k + 3) * 36 + o] = w.w;
    }
    int g = tid >> 5;
    int lane5 = tid & 31;
    int sc = lane5 & 7, eh = lane5 >> 3;
    int n = vb * 8 + g;
    int s0 = rs[n], s1 = rs[n + 1];
    float4 acc = gather4(csr, s0, s1, S, sc, eh);
    float deg = (float)(s1 - s0);
    deg = deg > 1.f ? deg : 1.f;
    float4 r4 = *(const float4*)(Rb + (size_t)n * HH + 4 * sc);
    float4 b4 = *(const float4*)(bias + 4 * sc);
    float4 v4;
    v4.x = acc.x / deg + r4.x + b4.x;
    v4.y = acc.y / deg + r4.y + b4.y;
    v4.z = acc.z / deg + r4.z + b4.z;
    v4.w = acc.w / deg + r4.w + b4.w;
    float ss = v4.x * v4.x + v4.y * v4.y + v4.z * v4.z + v4.w * v4.w;
    ss += __shfl_xor(ss, 1);
    ss += __shfl_xor(ss, 2);
    ss += __shfl_xor(ss, 4);
    float nrm = sqrtf(ss);
    nrm = nrm > 1e-12f ? nrm : 1e-12f;
    v4.x /= nrm; v4.y /= nrm; v4.z /= nrm; v4.w /= nrm;
    v4.x = v4.x > 0.f ? v4.x : 0.f;
    v4.y = v4.y > 0.f ? v4.y : 0.f;
    v4.z = v4.z > 0.f ? v4.z : 0.f;
    v4.w = v4.w > 0.f ? v4.w : 0.f;
    if (eh == 0) {
        sH[g][4 * sc + 0] = v4.x;
        sH[g][4 * sc + 1] = v4.y;
        sH[g][4 * sc + 2] = v4.z;
        sH[g][4 * sc + 3] = v4.w;
    }
    __syncthreads();
    int c = tid & 31;
    float aL = 0.f, aR = 0.f;
#pragma unroll
    for (int k = 0; k < HH; ++k) {
        float x = sH[g][k];
        aL += x * sWl[k * 36 + c];
        aR += x * sWr[k * 36 + c];
    }
    S2[(size_t)n * HH + c] = __float2half_rn(aL);
    Rb[(size_t)n * HH + c] = aR;
}

// ================= pull1 + final (fp16 S in) =================
__device__ __forceinline__ void pull1f_body(const int* __restrict__ csr,
                                            const int* __restrict__ rs,
                                            const __half* __restrict__ S,
                                            const float* __restrict__ R,
                                            const float* __restrict__ b1,
                                            const float* __restrict__ Wp,
                                            const float* __restrict__ bp,
                                            float* __restrict__ out, int vb, float* smem) {
    float* sWpT = smem;
    float* sH   = smem + HH * 36;
    int tid = threadIdx.x;
    {
        float4 a = ((const float4*)Wp)[tid];
        int e0 = tid * 4;
        int o = e0 >> 5, k = e0 & 31;
        sWpT[(k + 0) * 36 + o] = a.x;
        sWpT[(k + 1) * 36 + o] = a.y;
        sWpT[(k + 2) * 36 + o] = a.z;
        sWpT[(k + 3) * 36 + o] = a.w;
    }
    int g = tid >> 5;
    int lane5 = tid & 31;
    int sc = lane5 & 7, eh = lane5 >> 3;
    int n = vb * 8 + g;
    int s0 = rs[n], s1 = rs[n + 1];
    float4 acc = gather4(csr, s0, s1, S, sc, eh);
    float deg = (float)(s1 - s0);
    deg = deg > 1.f ? deg : 1.f;
    float4 r4 = *(const float4*)(R + (size_t)n * HH + 4 * sc);
    float4 b4 = *(const float4*)(b1 + 4 * sc);
    float4 v4;
    v4.x = acc.x / deg + r4.x + b4.x;
    v4.y = acc.y / deg + r4.y + b4.y;
    v4.z = acc.z / deg + r4.z + b4.z;
    v4.w = acc.w / deg + r4.w + b4.w;
    float ss = v4.x * v4.x + v4.y * v4.y + v4.z * v4.z + v4.w * v4.w;
    ss += __shfl_xor(ss, 1);
    ss += __shfl_xor(ss, 2);
    ss += __shfl_xor(ss, 4);
    float nrm = sqrtf(ss);
    nrm = nrm > 1e-12f ? nrm : 1e-12f;
    v4.x /= nrm; v4.y /= nrm; v4.z /= nrm; v4.w /= nrm;
    v4.x = v4.x > 0.f ? v4.x : 0.f;
    v4.y = v4.y > 0.f ? v4.y : 0.f;
    v4.z = v4.z > 0.f ? v4.z : 0.f;
    v4.w = v4.w > 0.f ? v4.w : 0.f;
    if (eh == 0) {
        sH[g * 36 + 4 * sc + 0] = v4.x;
        sH[g * 36 + 4 * sc + 1] = v4.y;
        sH[g * 36 + 4 * sc + 2] = v4.z;
        sH[g * 36 + 4 * sc + 3] = v4.w;
    }
    __syncthreads();
    int c = tid & 31;
    float a2f = bp[c];
#pragma unroll
    for (int k = 0; k < HH; ++k) a2f += sH[g * 36 + k] * sWpT[k * 36 + c];
    float s2 = a2f * a2f;
    s2 += __shfl_xor(s2, 1);
    s2 += __shfl_xor(s2, 2);
    s2 += __shfl_xor(s2, 4);
    s2 += __shfl_xor(s2, 8);
    s2 += __shfl_xor(s2, 16);
    float nrm2 = sqrtf(s2);
    nrm2 = nrm2 > 1e-12f ? nrm2 : 1e-12f;
    out[(size_t)n * HH + c] = a2f / nrm2;
}

__global__ void p4_k(const int* __restrict__ csrU, const int* __restrict__ rsU,
                     const __half* __restrict__ Si2, const float* __restrict__ Ru,
                     const float* __restrict__ b1_iu,
                     const float* __restrict__ wp_user, const float* __restrict__ bp_user,
                     const int* __restrict__ csrI, const int* __restrict__ rsI,
                     const __half* __restrict__ Su2, const float* __restrict__ Ri,
                     const float* __restrict__ b1_ui,
                     const float* __restrict__ wp_item, const float* __restrict__ bp_item,
                     float* __restrict__ out) {
    __shared__ float smem[HH * 36 + 8 * 36];
    int b = blockIdx.x;
    if (b < G_P0U) {
        pull1f_body(csrU, rsU, Si2, Ru, b1_iu, wp_user, bp_user, out, b, smem);
    } else {
        pull1f_body(csrI, rsI, Su2, Ri, b1_ui, wp_item, bp_item,
                    out + (size_t)NU * HH, b - G_P0U, smem);
    }
}

// ================= host =================

extern "C" void kernel_launch(void* const* d_in, const int* in_sizes, int n_in,
                              void* d_out, int out_size, void* d_ws, size_t ws_size,
                              hipStream_t stream) {
    const float* x_user = (const float*)d_in[0];
    const float* x_item = (const float*)d_in[1];
    const int* eu = (const int*)d_in[2];
    const int* ei = (const int*)d_in[3];
    const float* wl0_ui = (const float*)d_in[4];
    const float* b0_ui  = (const float*)d_in[5];
    const float* wr0_ui = (const float*)d_in[6];
    const float* wl0_iu = (const float*)d_in[7];
    const float* b0_iu  = (const float*)d_in[8];
    const float* wr0_iu = (const float*)d_in[9];
    const float* wl1_ui = (const float*)d_in[10];
    const float* b1_ui  = (const float*)d_in[11];
    const float* wr1_ui = (const float*)d_in[12];
    const float* wl1_iu = (const float*)d_in[13];
    const float* b1_iu  = (const float*)d_in[14];
    const float* wr1_iu = (const float*)d_in[15];
    const float* wp_user = (const float*)d_in[16];
    const float* bp_user = (const float*)d_in[17];
    const float* wp_item = (const float*)d_in[18];
    const float* bp_item = (const float*)d_in[19];
    float* out = (float*)d_out;
    (void)in_sizes; (void)n_in; (void)out_size; (void)ws_size;

    char* base = (char*)d_ws;
    size_t off = 0;
    auto take = [&](size_t bytes) -> size_t {
        size_t o = off;
        off += (bytes + 255) & ~(size_t)255;
        return o;
    };
    size_t o_rsU  = take((size_t)(NU + 1) * 4);
    size_t o_rsI  = take((size_t)(NI + 1) * 4);
    size_t o_cntU = take((size_t)NBU * NCH * 4);
    size_t o_cntI = take((size_t)NBI * NCH * 4);
    size_t o_csrU = take((size_t)NE * 4);
    size_t o_csrI = take((size_t)NE * 4);
    size_t o_partU = take((size_t)NE * 8);
    size_t o_partI = take((size_t)NE * 8);
    size_t o_Su = take((size_t)NU * HH * 2);   // fp16 message tables
    size_t o_Si = take((size_t)NI * HH * 2);
    size_t o_Su2 = take((size_t)NU * HH * 2);
    size_t o_Si2 = take((size_t)NI * HH * 2);
    size_t o_Ru = take((size_t)NU * HH * 4);   // f32 self tables
    size_t o_Ri = take((size_t)NI * HH * 4);

    int* rsU  = (int*)(base + o_rsU);
    int* rsI  = (int*)(base + o_rsI);
    int* cntU = (int*)(base + o_cntU);
    int* cntI = (int*)(base + o_cntI);
    int* csrU = (int*)(base + o_csrU);
    int* csrI = (int*)(base + o_csrI);
    int2* partU = (int2*)(base + o_partU);
    int2* partI = (int2*)(base + o_partI);
    __half* Su = (__half*)(base + o_Su);
    __half* Si = (__half*)(base + o_Si);
    __half* Su2 = (__half*)(base + o_Su2);
    __half* Si2 = (__half*)(base + o_Si2);
    float* Ru = (float*)(base + o_Ru);
    float* Ri = (float*)(base + o_Ri);

    // ---- radix CSR build (no global random atomics, no memset) ----
    cnt1_k<<<2 * NCH, 256, 0, stream>>>((const int4*)eu, (const int4*)ei, cntU, cntI);
    scan2_k<<<1, 1024, 0, stream>>>(cntU, NBU * NCH, cntI, NBI * NCH);
    part_k<<<2 * NCH, 256, 0, stream>>>((const int4*)eu, (const int4*)ei,
                                        cntU, cntI, partU, partI);
    build_k<<<NBU + NBI, 1024, 0, stream>>>(partU, partI, cntU, cntI,
                                            rsU, rsI, csrU, csrI);

    // ---- layer-0 projections via MFMA (f16 inputs, f32 accum) ----
    p1m_k<<<GPU_B + GPI_B, 256, 0, stream>>>(x_user, x_item, wl0_ui, wr0_iu,
                                             wl0_iu, wr0_ui, Su, Ru, Si, Ri);

    // ---- layer-0 pulls fused with layer-1 projections ----
    p23_k<<<G_P0I + G_P0U, 256, 0, stream>>>(csrI, rsI, Su, Ri, b0_ui, wl1_iu, wr1_ui, Si2,
                                             csrU, rsU, Si, Ru, b0_iu, wl1_ui, wr1_iu, Su2);

    // ---- layer-1 pulls + final projections -> out ----
    p4_k<<<G_P0U + G_P0I, 256, 0, stream>>>(csrU, rsU, Si2, Ru, b1_iu, wp_user, bp_user,
                                            csrI, rsI, Su2, Ri, b1_ui, wp_item, bp_item,
                                            out);
}

// Round 20
// 196.985 us; speedup vs baseline: 8.4353x; 1.0147x over previous
//
#include <hip/hip_runtime.h>
#include <hip/hip_fp16.h>

#define NU 100000
#define NI 50000
#define NE 819200
#define FIN 128
#define HH 32

#define NCH 200         // edge chunks of 4096
#define NBU 98          // user buckets of 1024 nodes
#define NBI 49          // item buckets of 1024 nodes

#define G_P0I 6250      // NI/8
#define G_P0U 12500     // NU/8
#define GPU_B 640       // user proj blocks
#define GPI_B 320       // item proj blocks

typedef _Float16 f16x8 __attribute__((ext_vector_type(8)));
typedef float f32x4 __attribute__((ext_vector_type(4)));

// ================= radix CSR build =================

__global__ void cnt1_k(const int4* __restrict__ eu4, const int4* __restrict__ ei4,
                       int* __restrict__ cntU, int* __restrict__ cntI) {
    __shared__ unsigned cnt[128];
    int b = blockIdx.x;
    int c, NB;
    const int4* D;
    int* M;
    if (b < NCH) { c = b; D = eu4; M = cntU; NB = NBU; }
    else         { c = b - NCH; D = ei4; M = cntI; NB = NBI; }
    int tid = threadIdx.x;
    if (tid < 128) cnt[tid] = 0u;
    __syncthreads();
    int base = c * 1024;
#pragma unroll
    for (int it = 0; it < 4; ++it) {
        int4 v = D[base + it * 256 + tid];
        atomicAdd(&cnt[v.x >> 10], 1u);
        atomicAdd(&cnt[v.y >> 10], 1u);
        atomicAdd(&cnt[v.z >> 10], 1u);
        atomicAdd(&cnt[v.w >> 10], 1u);
    }
    __syncthreads();
    for (int i = tid; i < NB; i += 256) M[i * NCH + c] = (int)cnt[i];
}

__global__ __launch_bounds__(1024) void scan2_k(int* __restrict__ aU, int nU,
                                                int* __restrict__ aI, int nI) {
    __shared__ int ts[1024];
    int t = threadIdx.x;
    for (int pass = 0; pass < 2; ++pass) {
        int* a = pass ? aI : aU;
        int n  = pass ? nI : nU;
        int nper = (n + 1023) / 1024;
        int beg = t * nper;
        int end = beg + nper; if (end > n) end = n;
        int s = 0;
        for (int i = beg; i < end; ++i) s += a[i];
        ts[t] = s;
        __syncthreads();
        int incl = s;
        for (int off = 1; off < 1024; off <<= 1) {
            int y = (t >= off) ? ts[t - off] : 0;
            __syncthreads();
            incl += y;
            ts[t] = incl;
            __syncthreads();
        }
        int run = incl - s;
        for (int i = beg; i < end; ++i) { int v = a[i]; a[i] = run; run += v; }
        __syncthreads();
    }
}

__global__ void part_k(const int4* __restrict__ eu4, const int4* __restrict__ ei4,
                       const int* __restrict__ cntU, const int* __restrict__ cntI,
                       int2* __restrict__ partU, int2* __restrict__ partI) {
    __shared__ unsigned cur[128];
    int b = blockIdx.x;
    int c, NB;
    const int4 *D, *P;
    const int* M;
    int2* out;
    if (b < NCH) { c = b; D = eu4; P = ei4; M = cntU; out = partU; NB = NBU; }
    else         { c = b - NCH; D = ei4; P = eu4; M = cntI; out = partI; NB = NBI; }
    int tid = threadIdx.x;
    for (int i = tid; i < NB; i += 256) cur[i] = (unsigned)M[i * NCH + c];
    __syncthreads();
    int base = c * 1024;
#pragma unroll
    for (int it = 0; it < 4; ++it) {
        int4 d = D[base + it * 256 + tid];
        int4 p = P[base + it * 256 + tid];
        unsigned s;
        s = atomicAdd(&cur[d.x >> 10], 1u); out[s] = make_int2(d.x, p.x);
        s = atomicAdd(&cur[d.y >> 10], 1u); out[s] = make_int2(d.y, p.y);
        s = atomicAdd(&cur[d.z >> 10], 1u); out[s] = make_int2(d.z, p.z);
        s = atomicAdd(&cur[d.w >> 10], 1u); out[s] = make_int2(d.w, p.w);
    }
}

// csr stores BYTE OFFSETS (payload << 6) of 64B S-rows
__global__ __launch_bounds__(1024) void build_k(const int2* __restrict__ partU,
                                                const int2* __restrict__ partI,
                                                const int* __restrict__ cntU,
                                                const int* __restrict__ cntI,
                                                int* __restrict__ rsU, int* __restrict__ rsI,
                                                int* __restrict__ csrU, int* __restrict__ csrI) {
    __shared__ unsigned dcnt[1024];
    __shared__ unsigned sc_[1024];
    int b = blockIdx.x;
    const int2* part;
    const int* M;
    int *rs, *csr;
    int bi, N, NB;
    if (b < NBU) { bi = b; part = partU; M = cntU; rs = rsU; csr = csrU; N = NU; NB = NBU; }
    else         { bi = b - NBU; part = partI; M = cntI; rs = rsI; csr = csrI; N = NI; NB = NBI; }
    int lo = bi * 1024;
    int bktbase = M[bi * NCH];
    int bktend = (bi + 1 < NB) ? M[(bi + 1) * NCH] : NE;
    int t = threadIdx.x;
    dcnt[t] = 0u;
    __syncthreads();
    for (int j = bktbase + t; j < bktend; j += 1024) {
        int2 p = part[j];
        atomicAdd(&dcnt[p.x - lo], 1u);
    }
    __syncthreads();
    unsigned cme = dcnt[t];
    sc_[t] = cme;
    __syncthreads();
    unsigned incl = cme;
    for (int off = 1; off < 1024; off <<= 1) {
        unsigned y = (t >= off) ? sc_[t - off] : 0u;
        __syncthreads();
        incl += y;
        sc_[t] = incl;
        __syncthreads();
    }
    unsigned excl = incl - cme;
    if (lo + t < N) rs[lo + t] = bktbase + (int)excl;
    if (bi == NB - 1 && t == 0) rs[N] = NE;
    __syncthreads();
    dcnt[t] = excl;
    __syncthreads();
    for (int j = bktbase + t; j < bktend; j += 1024) {
        int2 p = part[j];
        unsigned s = atomicAdd(&dcnt[p.x - lo], 1u);
        csr[bktbase + (int)s] = p.y << 6;
    }
}

// ======= proj128 via MFMA: per wave 16 nodes x 64 cols, B-frags in registers =======
__global__ __launch_bounds__(256) void p1m_k(const float* __restrict__ xu,
                                             const float* __restrict__ xi,
                                             const float* __restrict__ wl0_ui,
                                             const float* __restrict__ wr0_iu,
                                             const float* __restrict__ wl0_iu,
                                             const float* __restrict__ wr0_ui,
                                             __half* __restrict__ Su, float* __restrict__ Ru,
                                             __half* __restrict__ Si, float* __restrict__ Ri) {
    const float *X, *Wl, *Wr;
    __half* S;
    float* R;
    int N, nwv, wid;
    int b = blockIdx.x;
    if (b < GPU_B) {
        X = xu; Wl = wl0_ui; Wr = wr0_iu; S = Su; R = Ru; N = NU;
        nwv = GPU_B * 4; wid = b * 4 + (threadIdx.x >> 6);
    } else {
        int bb = b - GPU_B;
        X = xi; Wl = wl0_iu; Wr = wr0_ui; S = Si; R = Ri; N = NI;
        nwv = GPI_B * 4; wid = bb * 4 + (threadIdx.x >> 6);
    }
    int lane = threadIdx.x & 63;
    int l15 = lane & 15, kq = lane >> 4;
    f16x8 bf[4][4];
#pragma unroll
    for (int nt = 0; nt < 4; ++nt) {
        int col = nt * 16 + l15;
        const float* wrow = (col < 32) ? (Wl + (size_t)col * FIN)
                                       : (Wr + (size_t)(col - 32) * FIN);
#pragma unroll
        for (int ks = 0; ks < 4; ++ks) {
            int k0 = ks * 32 + kq * 8;
            float4 wa = *(const float4*)(wrow + k0);
            float4 wb = *(const float4*)(wrow + k0 + 4);
            f16x8 v;
            v[0] = (_Float16)wa.x; v[1] = (_Float16)wa.y;
            v[2] = (_Float16)wa.z; v[3] = (_Float16)wa.w;
            v[4] = (_Float16)wb.x; v[5] = (_Float16)wb.y;
            v[6] = (_Float16)wb.z; v[7] = (_Float16)wb.w;
            bf[ks][nt] = v;
        }
    }
    int tiles = (N + 15) >> 4;
    for (int t = wid; t < tiles; t += nwv) {
        int row = t * 16 + l15;
        if (row >= N) row = N - 1;
        const float* xrow = X + (size_t)row * FIN;
        f32x4 a0 = {0.f, 0.f, 0.f, 0.f};
        f32x4 a1 = {0.f, 0.f, 0.f, 0.f};
        f32x4 a2 = {0.f, 0.f, 0.f, 0.f};
        f32x4 a3 = {0.f, 0.f, 0.f, 0.f};
#pragma unroll
        for (int ks = 0; ks < 4; ++ks) {
            int k0 = ks * 32 + kq * 8;
            float4 xa = *(const float4*)(xrow + k0);
            float4 xb = *(const float4*)(xrow + k0 + 4);
            f16x8 af;
            af[0] = (_Float16)xa.x; af[1] = (_Float16)xa.y;
            af[2] = (_Float16)xa.z; af[3] = (_Float16)xa.w;
            af[4] = (_Float16)xb.x; af[5] = (_Float16)xb.y;
            af[6] = (_Float16)xb.z; af[7] = (_Float16)xb.w;
            a0 = __builtin_amdgcn_mfma_f32_16x16x32_f16(af, bf[ks][0], a0, 0, 0, 0);
            a1 = __builtin_amdgcn_mfma_f32_16x16x32_f16(af, bf[ks][1], a1, 0, 0, 0);
            a2 = __builtin_amdgcn_mfma_f32_16x16x32_f16(af, bf[ks][2], a2, 0, 0, 0);
            a3 = __builtin_amdgcn_mfma_f32_16x16x32_f16(af, bf[ks][3], a3, 0, 0, 0);
        }
        int rbase = t * 16 + kq * 4;
#pragma unroll
        for (int r = 0; r < 4; ++r) {
            int node = rbase + r;
            if (node < N) {
                _Float16* srow = (_Float16*)(S + (size_t)node * HH);
                srow[l15]      = (_Float16)a0[r];
                srow[16 + l15] = (_Float16)a1[r];
                float* rrow = R + (size_t)node * HH;
                rrow[l15]      = a2[r];
                rrow[16 + l15] = a3[r];
            }
        }
    }
}

// ==== gather: csrB holds byte offsets; packed fp16 accumulate; packed shfl reduce ====
__device__ __forceinline__ float4 gather4(const int* __restrict__ csrB, int s0, int s1,
                                          const __half* __restrict__ S, int sc, int eh) {
    const char* Sb = (const char*)S;
    __half2 acc01 = __floats2half2_rn(0.f, 0.f);
    __half2 acc23 = acc01;
    int j = s0 + eh;
    for (; j + 4 < s1; j += 8) {
        int o0 = csrB[j], o1 = csrB[j + 4];
        uint2 u0 = *(const uint2*)(Sb + (size_t)(unsigned)o0 + sc * 8);
        uint2 u1 = *(const uint2*)(Sb + (size_t)(unsigned)o1 + sc * 8);
        acc01 = __hadd2(acc01, __hadd2(*(__half2*)&u0.x, *(__half2*)&u1.x));
        acc23 = __hadd2(acc23, __hadd2(*(__half2*)&u0.y, *(__half2*)&u1.y));
    }
    if (j < s1) {
        int o0 = csrB[j];
        uint2 u0 = *(const uint2*)(Sb + (size_t)(unsigned)o0 + sc * 8);
        acc01 = __hadd2(acc01, *(__half2*)&u0.x);
        acc23 = __hadd2(acc23, *(__half2*)&u0.y);
    }
    // packed cross-slot reduce (lane bits 3,4)
    int p01 = *(int*)&acc01, p23 = *(int*)&acc23;
    int q01 = __shfl_xor(p01, 8);
    int q23 = __shfl_xor(p23, 8);
    acc01 = __hadd2(acc01, *(__half2*)&q01);
    acc23 = __hadd2(acc23, *(__half2*)&q23);
    p01 = *(int*)&acc01; p23 = *(int*)&acc23;
    q01 = __shfl_xor(p01, 16);
    q23 = __shfl_xor(p23, 16);
    acc01 = __hadd2(acc01, *(__half2*)&q01);
    acc23 = __hadd2(acc23, *(__half2*)&q23);
    float2 f01 = __half22float2(acc01);
    float2 f23 = __half22float2(acc23);
    return make_float4(f01.x, f01.y, f23.x, f23.y);
}

// ================= fused pull0 + proj32 (fp16 S in, fp16 S2 out) =================
__global__ void p23_k(const int* __restrict__ csrI, const int* __restrict__ rsI,
                      const __half* __restrict__ Su, float* __restrict__ Ri,
                      const float* __restrict__ b0_ui,
                      const float* __restrict__ wl1_iu, const float* __restrict__ wr1_ui,
                      __half* __restrict__ Si2,
                      const int* __restrict__ csrU, const int* __restrict__ rsU,
                      const __half* __restrict__ Si, float* __restrict__ Ru,
                      const float* __restrict__ b0_iu,
                      const float* __restrict__ wl1_ui, const float* __restrict__ wr1_iu,
                      __half* __restrict__ Su2) {
    __shared__ float sWl[HH * 36];
    __shared__ float sWr[HH * 36];
    __shared__ float sH[8][36];
    int b = blockIdx.x;
    const int *csr, *rs;
    const __half* S;
    const float *bias, *Wl, *Wr;
    float* Rb;
    __half* S2;
    int vb;
    if (b < G_P0I) {
        csr = csrI; rs = rsI; S = Su; Rb = Ri; bias = b0_ui;
        Wl = wl1_iu; Wr = wr1_ui; S2 = Si2; vb = b;
    } else {
        csr = csrU; rs = rsU; S = Si; Rb = Ru; bias = b0_iu;
        Wl = wl1_ui; Wr = wr1_iu; S2 = Su2; vb = b - G_P0I;
    }
    int tid = threadIdx.x;
    {
        float4 a = ((const float4*)Wl)[tid];
        float4 w = ((const float4*)Wr)[tid];
        int e0 = tid * 4;
        int o = e0 >> 5, k = e0 & 31;
        sWl[(k + 0) * 36 + o] = a.x;
        sWl[(k + 1) * 36 + o] = a.y;
        sWl[(k + 2) * 36 + o] = a.z;
        sWl[(k + 3) * 36 + o] = a.w;
        sWr[(k + 0) * 36 + o] = w.x;
        sWr[(k + 1) * 36 + o] = w.y;
        sWr[(k + 2) * 36 + o] = w.z;
        sWr[(k + 3) * 36 + o] = w.w;
    }
    int g = tid >> 5;
    int lane5 = tid & 31;
    int sc = lane5 & 7, eh = lane5 >> 3;
    int n = vb * 8 + g;
    int s0 = rs[n], s1 = rs[n + 1];
    float4 acc = gather4(csr, s0, s1, S, sc, eh);
    float deg = (float)(s1 - s0);
    deg = deg > 1.f ? deg : 1.f;
    float4 r4 = *(const float4*)(Rb + (size_t)n * HH + 4 * sc);
    float4 b4 = *(const float4*)(bias + 4 * sc);
    float4 v4;
    v4.x = acc.x / deg + r4.x + b4.x;
    v4.y = acc.y / deg + r4.y + b4.y;
    v4.z = acc.z / deg + r4.z + b4.z;
    v4.w = acc.w / deg + r4.w + b4.w;
    float ss = v4.x * v4.x + v4.y * v4.y + v4.z * v4.z + v4.w * v4.w;
    ss += __shfl_xor(ss, 1);
    ss += __shfl_xor(ss, 2);
    ss += __shfl_xor(ss, 4);
    float nrm = sqrtf(ss);
    nrm = nrm > 1e-12f ? nrm : 1e-12f;
    v4.x /= nrm; v4.y /= nrm; v4.z /= nrm; v4.w /= nrm;
    v4.x = v4.x > 0.f ? v4.x : 0.f;
    v4.y = v4.y > 0.f ? v4.y : 0.f;
    v4.z = v4.z > 0.f ? v4.z : 0.f;
    v4.w = v4.w > 0.f ? v4.w : 0.f;
    if (eh == 0) {
        sH[g][4 * sc + 0] = v4.x;
        sH[g][4 * sc + 1] = v4.y;
        sH[g][4 * sc + 2] = v4.z;
        sH[g][4 * sc + 3] = v4.w;
    }
    __syncthreads();
    int c = tid & 31;
    float aL = 0.f, aR = 0.f;
#pragma unroll
    for (int k = 0; k < HH; ++k) {
        float x = sH[g][k];
        aL += x * sWl[k * 36 + c];
        aR += x * sWr[k * 36 + c];
    }
    S2[(size_t)n * HH + c] = __float2half_rn(aL);
    Rb[(size_t)n * HH + c] = aR;
}

// ================= pull1 + final (fp16 S in) =================
__device__ __forceinline__ void pull1f_body(const int* __restrict__ csr,
                                            const int* __restrict__ rs,
                                            const __half* __restrict__ S,
                                            const float* __restrict__ R,
                                            const float* __restrict__ b1,
                                            const float* __restrict__ Wp,
                                            const float* __restrict__ bp,
                                            float* __restrict__ out, int vb, float* smem) {
    float* sWpT = smem;
    float* sH   = smem + HH * 36;
    int tid = threadIdx.x;
    {
        float4 a = ((const float4*)Wp)[tid];
        int e0 = tid * 4;
        int o = e0 >> 5, k = e0 & 31;
        sWpT[(k + 0) * 36 + o] = a.x;
        sWpT[(k + 1) * 36 + o] = a.y;
        sWpT[(k + 2) * 36 + o] = a.z;
        sWpT[(k + 3) * 36 + o] = a.w;
    }
    int g = tid >> 5;
    int lane5 = tid & 31;
    int sc = lane5 & 7, eh = lane5 >> 3;
    int n = vb * 8 + g;
    int s0 = rs[n], s1 = rs[n + 1];
    float4 acc = gather4(csr, s0, s1, S, sc, eh);
    float deg = (float)(s1 - s0);
    deg = deg > 1.f ? deg : 1.f;
    float4 r4 = *(const float4*)(R + (size_t)n * HH + 4 * sc);
    float4 b4 = *(const float4*)(b1 + 4 * sc);
    float4 v4;
    v4.x = acc.x / deg + r4.x + b4.x;
    v4.y = acc.y / deg + r4.y + b4.y;
    v4.z = acc.z / deg + r4.z + b4.z;
    v4.w = acc.w / deg + r4.w + b4.w;
    float ss = v4.x * v4.x + v4.y * v4.y + v4.z * v4.z + v4.w * v4.w;
    ss += __shfl_xor(ss, 1);
    ss += __shfl_xor(ss, 2);
    ss += __shfl_xor(ss, 4);
    float nrm = sqrtf(ss);
    nrm = nrm > 1e-12f ? nrm : 1e-12f;
    v4.x /= nrm; v4.y /= nrm; v4.z /= nrm; v4.w /= nrm;
    v4.x = v4.x > 0.f ? v4.x : 0.f;
    v4.y = v4.y > 0.f ? v4.y : 0.f;
    v4.z = v4.z > 0.f ? v4.z : 0.f;
    v4.w = v4.w > 0.f ? v4.w : 0.f;
    if (eh == 0) {
        sH[g * 36 + 4 * sc + 0] = v4.x;
        sH[g * 36 + 4 * sc + 1] = v4.y;
        sH[g * 36 + 4 * sc + 2] = v4.z;
        sH[g * 36 + 4 * sc + 3] = v4.w;
    }
    __syncthreads();
    int c = tid & 31;
    float a2f = bp[c];
#pragma unroll
    for (int k = 0; k < HH; ++k) a2f += sH[g * 36 + k] * sWpT[k * 36 + c];
    float s2 = a2f * a2f;
    s2 += __shfl_xor(s2, 1);
    s2 += __shfl_xor(s2, 2);
    s2 += __shfl_xor(s2, 4);
    s2 += __shfl_xor(s2, 8);
    s2 += __shfl_xor(s2, 16);
    float nrm2 = sqrtf(s2);
    nrm2 = nrm2 > 1e-12f ? nrm2 : 1e-12f;
    out[(size_t)n * HH + c] = a2f / nrm2;
}

__global__ void p4_k(const int* __restrict__ csrU, const int* __restrict__ rsU,
                     const __half* __restrict__ Si2, const float* __restrict__ Ru,
                     const float* __restrict__ b1_iu,
                     const float* __restrict__ wp_user, const float* __restrict__ bp_user,
                     const int* __restrict__ csrI, const int* __restrict__ rsI,
                     const __half* __restrict__ Su2, const float* __restrict__ Ri,
                     const float* __restrict__ b1_ui,
                     const float* __restrict__ wp_item, const float* __restrict__ bp_item,
                     float* __restrict__ out) {
    __shared__ float smem[HH * 36 + 8 * 36];
    int b = blockIdx.x;
    if (b < G_P0U) {
        pull1f_body(csrU, rsU, Si2, Ru, b1_iu, wp_user, bp_user, out, b, smem);
    } else {
        pull1f_body(csrI, rsI, Su2, Ri, b1_ui, wp_item, bp_item,
                    out + (size_t)NU * HH, b - G_P0U, smem);
    }
}

// ================= host =================

extern "C" void kernel_launch(void* const* d_in, const int* in_sizes, int n_in,
                              void* d_out, int out_size, void* d_ws, size_t ws_size,
                              hipStream_t stream) {
    const float* x_user = (const float*)d_in[0];
    const float* x_item = (const float*)d_in[1];
    const int* eu = (const int*)d_in[2];
    const int* ei = (const int*)d_in[3];
    const float* wl0_ui = (const float*)d_in[4];
    const float* b0_ui  = (const float*)d_in[5];
    const float* wr0_ui = (const float*)d_in[6];
    const float* wl0_iu = (const float*)d_in[7];
    const float* b0_iu  = (const float*)d_in[8];
    const float* wr0_iu = (const float*)d_in[9];
    const float* wl1_ui = (const float*)d_in[10];
    const float* b1_ui  = (const float*)d_in[11];
    const float* wr1_ui = (const float*)d_in[12];
    const float* wl1_iu = (const float*)d_in[13];
    const float* b1_iu  = (const float*)d_in[14];
    const float* wr1_iu = (const float*)d_in[15];
    const float* wp_user = (const float*)d_in[16];
    const float* bp_user = (const float*)d_in[17];
    const float* wp_item = (const float*)d_in[18];
    const float* bp_item = (const float*)d_in[19];
    float* out = (float*)d_out;
    (void)in_sizes; (void)n_in; (void)out_size; (void)ws_size;

    char* base = (char*)d_ws;
    size_t off = 0;
    auto take = [&](size_t bytes) -> size_t {
        size_t o = off;
        off += (bytes + 255) & ~(size_t)255;
        return o;
    };
    size_t o_rsU  = take((size_t)(NU + 1) * 4);
    size_t o_rsI  = take((size_t)(NI + 1) * 4);
    size_t o_cntU = take((size_t)NBU * NCH * 4);
    size_t o_cntI = take((size_t)NBI * NCH * 4);
    size_t o_csrU = take((size_t)NE * 4);
    size_t o_csrI = take((size_t)NE * 4);
    size_t o_partU = take((size_t)NE * 8);
    size_t o_partI = take((size_t)NE * 8);
    size_t o_Su = take((size_t)NU * HH * 2);   // fp16 message tables
    size_t o_Si = take((size_t)NI * HH * 2);
    size_t o_Su2 = take((size_t)NU * HH * 2);
    size_t o_Si2 = take((size_t)NI * HH * 2);
    size_t o_Ru = take((size_t)NU * HH * 4);   // f32 self tables
    size_t o_Ri = take((size_t)NI * HH * 4);

    int* rsU  = (int*)(base + o_rsU);
    int* rsI  = (int*)(base + o_rsI);
    int* cntU = (int*)(base + o_cntU);
    int* cntI = (int*)(base + o_cntI);
    int* csrU = (int*)(base + o_csrU);
    int* csrI = (int*)(base + o_csrI);
    int2* partU = (int2*)(base + o_partU);
    int2* partI = (int2*)(base + o_partI);
    __half* Su = (__half*)(base + o_Su);
    __half* Si = (__half*)(base + o_Si);
    __half* Su2 = (__half*)(base + o_Su2);
    __half* Si2 = (__half*)(base + o_Si2);
    float* Ru = (float*)(base + o_Ru);
    float* Ri = (float*)(base + o_Ri);

    // ---- radix CSR build (no global random atomics, no memset) ----
    cnt1_k<<<2 * NCH, 256, 0, stream>>>((const int4*)eu, (const int4*)ei, cntU, cntI);
    scan2_k<<<1, 1024, 0, stream>>>(cntU, NBU * NCH, cntI, NBI * NCH);
    part_k<<<2 * NCH, 256, 0, stream>>>((const int4*)eu, (const int4*)ei,
                                        cntU, cntI, partU, partI);
    build_k<<<NBU + NBI, 1024, 0, stream>>>(partU, partI, cntU, cntI,
                                            rsU, rsI, csrU, csrI);

    // ---- layer-0 projections via MFMA (f16 inputs, f32 accum) ----
    p1m_k<<<GPU_B + GPI_B, 256, 0, stream>>>(x_user, x_item, wl0_ui, wr0_iu,
                                             wl0_iu, wr0_ui, Su, Ru, Si, Ri);

    // ---- layer-0 pulls fused with layer-1 projections ----
    p23_k<<<G_P0I + G_P0U, 256, 0, stream>>>(csrI, rsI, Su, Ri, b0_ui, wl1_iu, wr1_ui, Si2,
                                             csrU, rsU, Si, Ru, b0_iu, wl1_ui, wr1_iu, Su2);

    // ---- layer-1 pulls + final projections -> out ----
    p4_k<<<G_P0U + G_P0I, 256, 0, stream>>>(csrU, rsU, Si2, Ru, b1_iu, wp_user, bp_user,
                                            csrI, rsI, Su2, Ri, b1_ui, wp_item, bp_item,
                                            out);
}

// Round 22
// 195.178 us; speedup vs baseline: 8.5134x; 1.0093x over previous
//
#include <hip/hip_runtime.h>
#include <hip/hip_fp16.h>

#define NU 100000
#define NI 50000
#define NE 819200
#define FIN 128
#define HH 32

#define NCH 200         // edge chunks of 4096
#define NBU 98          // user buckets of 1024 nodes
#define NBI 49          // item buckets of 1024 nodes

#define G_P0I 6250      // NI/8
#define G_P0U 12500     // NU/8
#define GPU_B 640       // user proj blocks
#define GPI_B 320       // item proj blocks

typedef _Float16 f16x8 __attribute__((ext_vector_type(8)));
typedef float f32x4 __attribute__((ext_vector_type(4)));

// ================= radix CSR build =================

__global__ void cnt1_k(const int4* __restrict__ eu4, const int4* __restrict__ ei4,
                       int* __restrict__ cntU, int* __restrict__ cntI) {
    __shared__ unsigned cnt[128];
    int b = blockIdx.x;
    int c, NB;
    const int4* D;
    int* M;
    if (b < NCH) { c = b; D = eu4; M = cntU; NB = NBU; }
    else         { c = b - NCH; D = ei4; M = cntI; NB = NBI; }
    int tid = threadIdx.x;
    if (tid < 128) cnt[tid] = 0u;
    __syncthreads();
    int base = c * 1024;
#pragma unroll
    for (int it = 0; it < 4; ++it) {
        int4 v = D[base + it * 256 + tid];
        atomicAdd(&cnt[v.x >> 10], 1u);
        atomicAdd(&cnt[v.y >> 10], 1u);
        atomicAdd(&cnt[v.z >> 10], 1u);
        atomicAdd(&cnt[v.w >> 10], 1u);
    }
    __syncthreads();
    for (int i = tid; i < NB; i += 256) M[i * NCH + c] = (int)cnt[i];
}

__global__ __launch_bounds__(1024) void scan2_k(int* __restrict__ aU, int nU,
                                                int* __restrict__ aI, int nI) {
    __shared__ int ts[1024];
    int t = threadIdx.x;
    for (int pass = 0; pass < 2; ++pass) {
        int* a = pass ? aI : aU;
        int n  = pass ? nI : nU;
        int nper = (n + 1023) / 1024;
        int beg = t * nper;
        int end = beg + nper; if (end > n) end = n;
        int s = 0;
        for (int i = beg; i < end; ++i) s += a[i];
        ts[t] = s;
        __syncthreads();
        int incl = s;
        for (int off = 1; off < 1024; off <<= 1) {
            int y = (t >= off) ? ts[t - off] : 0;
            __syncthreads();
            incl += y;
            ts[t] = incl;
            __syncthreads();
        }
        int run = incl - s;
        for (int i = beg; i < end; ++i) { int v = a[i]; a[i] = run; run += v; }
        __syncthreads();
    }
}

__global__ void part_k(const int4* __restrict__ eu4, const int4* __restrict__ ei4,
                       const int* __restrict__ cntU, const int* __restrict__ cntI,
                       int2* __restrict__ partU, int2* __restrict__ partI) {
    __shared__ unsigned cur[128];
    int b = blockIdx.x;
    int c, NB;
    const int4 *D, *P;
    const int* M;
    int2* out;
    if (b < NCH) { c = b; D = eu4; P = ei4; M = cntU; out = partU; NB = NBU; }
    else         { c = b - NCH; D = ei4; P = eu4; M = cntI; out = partI; NB = NBI; }
    int tid = threadIdx.x;
    for (int i = tid; i < NB; i += 256) cur[i] = (unsigned)M[i * NCH + c];
    __syncthreads();
    int base = c * 1024;
#pragma unroll
    for (int it = 0; it < 4; ++it) {
        int4 d = D[base + it * 256 + tid];
        int4 p = P[base + it * 256 + tid];
        unsigned s;
        s = atomicAdd(&cur[d.x >> 10], 1u); out[s] = make_int2(d.x, p.x);
        s = atomicAdd(&cur[d.y >> 10], 1u); out[s] = make_int2(d.y, p.y);
        s = atomicAdd(&cur[d.z >> 10], 1u); out[s] = make_int2(d.z, p.z);
        s = atomicAdd(&cur[d.w >> 10], 1u); out[s] = make_int2(d.w, p.w);
    }
}

// csr stores BYTE OFFSETS (payload << 6) of 64B S-rows
__global__ __launch_bounds__(1024) void build_k(const int2* __restrict__ partU,
                                                const int2* __restrict__ partI,
                                                const int* __restrict__ cntU,
                                                const int* __restrict__ cntI,
                                                int* __restrict__ rsU, int* __restrict__ rsI,
                                                int* __restrict__ csrU, int* __restrict__ csrI) {
    __shared__ unsigned dcnt[1024];
    __shared__ unsigned sc_[1024];
    int b = blockIdx.x;
    const int2* part;
    const int* M;
    int *rs, *csr;
    int bi, N, NB;
    if (b < NBU) { bi = b; part = partU; M = cntU; rs = rsU; csr = csrU; N = NU; NB = NBU; }
    else         { bi = b - NBU; part = partI; M = cntI; rs = rsI; csr = csrI; N = NI; NB = NBI; }
    int lo = bi * 1024;
    int bktbase = M[bi * NCH];
    int bktend = (bi + 1 < NB) ? M[(bi + 1) * NCH] : NE;
    int t = threadIdx.x;
    dcnt[t] = 0u;
    __syncthreads();
    for (int j = bktbase + t; j < bktend; j += 1024) {
        int2 p = part[j];
        atomicAdd(&dcnt[p.x - lo], 1u);
    }
    __syncthreads();
    unsigned cme = dcnt[t];
    sc_[t] = cme;
    __syncthreads();
    unsigned incl = cme;
    for (int off = 1; off < 1024; off <<= 1) {
        unsigned y = (t >= off) ? sc_[t - off] : 0u;
        __syncthreads();
        incl += y;
        sc_[t] = incl;
        __syncthreads();
    }
    unsigned excl = incl - cme;
    if (lo + t < N) rs[lo + t] = bktbase + (int)excl;
    if (bi == NB - 1 && t == 0) rs[N] = NE;
    __syncthreads();
    dcnt[t] = excl;
    __syncthreads();
    for (int j = bktbase + t; j < bktend; j += 1024) {
        int2 p = part[j];
        unsigned s = atomicAdd(&dcnt[p.x - lo], 1u);
        csr[bktbase + (int)s] = p.y << 6;
    }
}

// ======= proj128 via MFMA: per wave 16 nodes x 64 cols, B-frags in registers =======
__global__ __launch_bounds__(256) void p1m_k(const float* __restrict__ xu,
                                             const float* __restrict__ xi,
                                             const float* __restrict__ wl0_ui,
                                             const float* __restrict__ wr0_iu,
                                             const float* __restrict__ wl0_iu,
                                             const float* __restrict__ wr0_ui,
                                             __half* __restrict__ Su, float* __restrict__ Ru,
                                             __half* __restrict__ Si, float* __restrict__ Ri) {
    const float *X, *Wl, *Wr;
    __half* S;
    float* R;
    int N, nwv, wid;
    int b = blockIdx.x;
    if (b < GPU_B) {
        X = xu; Wl = wl0_ui; Wr = wr0_iu; S = Su; R = Ru; N = NU;
        nwv = GPU_B * 4; wid = b * 4 + (threadIdx.x >> 6);
    } else {
        int bb = b - GPU_B;
        X = xi; Wl = wl0_iu; Wr = wr0_ui; S = Si; R = Ri; N = NI;
        nwv = GPI_B * 4; wid = bb * 4 + (threadIdx.x >> 6);
    }
    int lane = threadIdx.x & 63;
    int l15 = lane & 15, kq = lane >> 4;
    f16x8 bf[4][4];
#pragma unroll
    for (int nt = 0; nt < 4; ++nt) {
        int col = nt * 16 + l15;
        const float* wrow = (col < 32) ? (Wl + (size_t)col * FIN)
                                       : (Wr + (size_t)(col - 32) * FIN);
#pragma unroll
        for (int ks = 0; ks < 4; ++ks) {
            int k0 = ks * 32 + kq * 8;
            float4 wa = *(const float4*)(wrow + k0);
            float4 wb = *(const float4*)(wrow + k0 + 4);
            f16x8 v;
            v[0] = (_Float16)wa.x; v[1] = (_Float16)wa.y;
            v[2] = (_Float16)wa.z; v[3] = (_Float16)wa.w;
            v[4] = (_Float16)wb.x; v[5] = (_Float16)wb.y;
            v[6] = (_Float16)wb.z; v[7] = (_Float16)wb.w;
            bf[ks][nt] = v;
        }
    }
    int tiles = (N + 15) >> 4;
    for (int t = wid; t < tiles; t += nwv) {
        int row = t * 16 + l15;
        if (row >= N) row = N - 1;
        const float* xrow = X + (size_t)row * FIN;
        f32x4 a0 = {0.f, 0.f, 0.f, 0.f};
        f32x4 a1 = {0.f, 0.f, 0.f, 0.f};
        f32x4 a2 = {0.f, 0.f, 0.f, 0.f};
        f32x4 a3 = {0.f, 0.f, 0.f, 0.f};
#pragma unroll
        for (int ks = 0; ks < 4; ++ks) {
            int k0 = ks * 32 + kq * 8;
            float4 xa = *(const float4*)(xrow + k0);
            float4 xb = *(const float4*)(xrow + k0 + 4);
            f16x8 af;
            af[0] = (_Float16)xa.x; af[1] = (_Float16)xa.y;
            af[2] = (_Float16)xa.z; af[3] = (_Float16)xa.w;
            af[4] = (_Float16)xb.x; af[5] = (_Float16)xb.y;
            af[6] = (_Float16)xb.z; af[7] = (_Float16)xb.w;
            a0 = __builtin_amdgcn_mfma_f32_16x16x32_f16(af, bf[ks][0], a0, 0, 0, 0);
            a1 = __builtin_amdgcn_mfma_f32_16x16x32_f16(af, bf[ks][1], a1, 0, 0, 0);
            a2 = __builtin_amdgcn_mfma_f32_16x16x32_f16(af, bf[ks][2], a2, 0, 0, 0);
            a3 = __builtin_amdgcn_mfma_f32_16x16x32_f16(af, bf[ks][3], a3, 0, 0, 0);
        }
        int rbase = t * 16 + kq * 4;
#pragma unroll
        for (int r = 0; r < 4; ++r) {
            int node = rbase + r;
            if (node < N) {
                _Float16* srow = (_Float16*)(S + (size_t)node * HH);
                srow[l15]      = (_Float16)a0[r];
                srow[16 + l15] = (_Float16)a1[r];
                float* rrow = R + (size_t)node * HH;
                rrow[l15]      = a2[r];
                rrow[16 + l15] = a3[r];
            }
        }
    }
}

// ==== gather8: lane = (sc in [0,4): uint4 16B chunk, eh in [0,8): edge slot) ====
struct F8 { float4 lo, hi; };

__device__ __forceinline__ F8 gather8(const int* __restrict__ csrB, int s0, int s1,
                                      const __half* __restrict__ S, int sc, int eh) {
    const char* Sb = (const char*)S;
    __half2 z = __floats2half2_rn(0.f, 0.f);
    __half2 a0 = z, a1 = z, a2 = z, a3 = z;
    for (int j = s0 + eh; j < s1; j += 8) {
        int o = csrB[j];
        uint4 u = *(const uint4*)(Sb + (size_t)(unsigned)o + sc * 16);
        a0 = __hadd2(a0, *(__half2*)&u.x);
        a1 = __hadd2(a1, *(__half2*)&u.y);
        a2 = __hadd2(a2, *(__half2*)&u.z);
        a3 = __hadd2(a3, *(__half2*)&u.w);
    }
    // reduce across eh slots (lane bits 2,3,4)
#pragma unroll
    for (int m = 4; m <= 16; m <<= 1) {
        int p0 = *(int*)&a0, p1 = *(int*)&a1, p2 = *(int*)&a2, p3 = *(int*)&a3;
        int q0 = __shfl_xor(p0, m);
        int q1 = __shfl_xor(p1, m);
        int q2 = __shfl_xor(p2, m);
        int q3 = __shfl_xor(p3, m);
        a0 = __hadd2(a0, *(__half2*)&q0);
        a1 = __hadd2(a1, *(__half2*)&q1);
        a2 = __hadd2(a2, *(__half2*)&q2);
        a3 = __hadd2(a3, *(__half2*)&q3);
    }
    float2 f0 = __half22float2(a0);
    float2 f1 = __half22float2(a1);
    float2 f2 = __half22float2(a2);
    float2 f3 = __half22float2(a3);
    F8 r;
    r.lo = make_float4(f0.x, f0.y, f1.x, f1.y);
    r.hi = make_float4(f2.x, f2.y, f3.x, f3.y);
    return r;
}

// ================= fused pull0 + proj32 (fp16 S in, fp16 S2 out) =================
__global__ void p23_k(const int* __restrict__ csrI, const int* __restrict__ rsI,
                      const __half* __restrict__ Su, float* __restrict__ Ri,
                      const float* __restrict__ b0_ui,
                      const float* __restrict__ wl1_iu, const float* __restrict__ wr1_ui,
                      __half* __restrict__ Si2,
                      const int* __restrict__ csrU, const int* __restrict__ rsU,
                      const __half* __restrict__ Si, float* __restrict__ Ru,
                      const float* __restrict__ b0_iu,
                      const float* __restrict__ wl1_ui, const float* __restrict__ wr1_iu,
                      __half* __restrict__ Su2) {
    __shared__ float sWl[HH * 36];
    __shared__ float sWr[HH * 36];
    __shared__ float sH[8][36];
    int b = blockIdx.x;
    const int *csr, *rs;
    const __half* S;
    const float *bias, *Wl, *Wr;
    float* Rb;
    __half* S2;
    int vb;
    if (b < G_P0I) {
        csr = csrI; rs = rsI; S = Su; Rb = Ri; bias = b0_ui;
        Wl = wl1_iu; Wr = wr1_ui; S2 = Si2; vb = b;
    } else {
        csr = csrU; rs = rsU; S = Si; Rb = Ru; bias = b0_iu;
        Wl = wl1_ui; Wr = wr1_iu; S2 = Su2; vb = b - G_P0I;
    }
    int tid = threadIdx.x;
    {
        float4 a = ((const float4*)Wl)[tid];
        float4 w = ((const float4*)Wr)[tid];
        int e0 = tid * 4;
        int o = e0 >> 5, k = e0 & 31;
        sWl[(k + 0) * 36 + o] = a.x;
        sWl[(k + 1) * 36 + o] = a.y;
        sWl[(k + 2) * 36 + o] = a.z;
        sWl[(k + 3) * 36 + o] = a.w;
        sWr[(k + 0) * 36 + o] = w.x;
        sWr[(k + 1) * 36 + o] = w.y;
        sWr[(k + 2) * 36 + o] = w.z;
        sWr[(k + 3) * 36 + o] = w.w;
    }
    int g = tid >> 5;
    int lane5 = tid & 31;
    int sc = lane5 & 3, eh = lane5 >> 2;
    int n = vb * 8 + g;
    int s0 = rs[n], s1 = rs[n + 1];
    F8 acc = gather8(csr, s0, s1, S, sc, eh);
    float deg = (float)(s1 - s0);
    deg = deg > 1.f ? deg : 1.f;
    float inv = 1.f / deg;
    const float* rrow = Rb + (size_t)n * HH + 8 * sc;
    float4 rA = *(const float4*)(rrow);
    float4 rB = *(const float4*)(rrow + 4);
    float4 bA = *(const float4*)(bias + 8 * sc);
    float4 bB = *(const float4*)(bias + 8 * sc + 4);
    float4 vA, vB;
    vA.x = acc.lo.x * inv + rA.x + bA.x;
    vA.y = acc.lo.y * inv + rA.y + bA.y;
    vA.z = acc.lo.z * inv + rA.z + bA.z;
    vA.w = acc.lo.w * inv + rA.w + bA.w;
    vB.x = acc.hi.x * inv + rB.x + bB.x;
    vB.y = acc.hi.y * inv + rB.y + bB.y;
    vB.z = acc.hi.z * inv + rB.z + bB.z;
    vB.w = acc.hi.w * inv + rB.w + bB.w;
    float ss = vA.x * vA.x + vA.y * vA.y + vA.z * vA.z + vA.w * vA.w
             + vB.x * vB.x + vB.y * vB.y + vB.z * vB.z + vB.w * vB.w;
    ss += __shfl_xor(ss, 1);
    ss += __shfl_xor(ss, 2);
    float nrm = sqrtf(ss);
    nrm = nrm > 1e-12f ? nrm : 1e-12f;
    float rinv = 1.f / nrm;
    vA.x *= rinv; vA.y *= rinv; vA.z *= rinv; vA.w *= rinv;
    vB.x *= rinv; vB.y *= rinv; vB.z *= rinv; vB.w *= rinv;
    vA.x = vA.x > 0.f ? vA.x : 0.f;
    vA.y = vA.y > 0.f ? vA.y : 0.f;
    vA.z = vA.z > 0.f ? vA.z : 0.f;
    vA.w = vA.w > 0.f ? vA.w : 0.f;
    vB.x = vB.x > 0.f ? vB.x : 0.f;
    vB.y = vB.y > 0.f ? vB.y : 0.f;
    vB.z = vB.z > 0.f ? vB.z : 0.f;
    vB.w = vB.w > 0.f ? vB.w : 0.f;
    if (eh == 0) {
        float* hs = &sH[g][8 * sc];
        hs[0] = vA.x; hs[1] = vA.y; hs[2] = vA.z; hs[3] = vA.w;
        hs[4] = vB.x; hs[5] = vB.y; hs[6] = vB.z; hs[7] = vB.w;
    }
    __syncthreads();
    int c = tid & 31;
    float aL = 0.f, aR = 0.f;
#pragma unroll
    for (int k = 0; k < HH; ++k) {
        float x = sH[g][k];
        aL += x * sWl[k * 36 + c];
        aR += x * sWr[k * 36 + c];
    }
    S2[(size_t)n * HH + c] = __float2half_rn(aL);
    Rb[(size_t)n * HH + c] = aR;
}

// ================= pull1 + final (fp16 S in) =================
__device__ __forceinline__ void pull1f_body(const int* __restrict__ csr,
                                            const int* __restrict__ rs,
                                            const __half* __restrict__ S,
                                            const float* __restrict__ R,
                                            const float* __restrict__ b1,
                                            const float* __restrict__ Wp,
                                            const float* __restrict__ bp,
                                            float* __restrict__ out, int vb, float* smem) {
    float* sWpT = smem;
    float* sH   = smem + HH * 36;
    int tid = threadIdx.x;
    {
        float4 a = ((const float4*)Wp)[tid];
        int e0 = tid * 4;
        int o = e0 >> 5, k = e0 & 31;
        sWpT[(k + 0) * 36 + o] = a.x;
        sWpT[(k + 1) * 36 + o] = a.y;
        sWpT[(k + 2) * 36 + o] = a.z;
        sWpT[(k + 3) * 36 + o] = a.w;
    }
    int g = tid >> 5;
    int lane5 = tid & 31;
    int sc = lane5 & 3, eh = lane5 >> 2;
    int n = vb * 8 + g;
    int s0 = rs[n], s1 = rs[n + 1];
    F8 acc = gather8(csr, s0, s1, S, sc, eh);
    float deg = (float)(s1 - s0);
    deg = deg > 1.f ? deg : 1.f;
    float inv = 1.f / deg;
    const float* rrow = R + (size_t)n * HH + 8 * sc;
    float4 rA = *(const float4*)(rrow);
    float4 rB = *(const float4*)(rrow + 4);
    float4 bA = *(const float4*)(b1 + 8 * sc);
    float4 bB = *(const float4*)(b1 + 8 * sc + 4);
    float4 vA, vB;
    vA.x = acc.lo.x * inv + rA.x + bA.x;
    vA.y = acc.lo.y * inv + rA.y + bA.y;
    vA.z = acc.lo.z * inv + rA.z + bA.z;
    vA.w = acc.lo.w * inv + rA.w + bA.w;
    vB.x = acc.hi.x * inv + rB.x + bB.x;
    vB.y = acc.hi.y * inv + rB.y + bB.y;
    vB.z = acc.hi.z * inv + rB.z + bB.z;
    vB.w = acc.hi.w * inv + rB.w + bB.w;
    float ss = vA.x * vA.x + vA.y * vA.y + vA.z * vA.z + vA.w * vA.w
             + vB.x * vB.x + vB.y * vB.y + vB.z * vB.z + vB.w * vB.w;
    ss += __shfl_xor(ss, 1);
    ss += __shfl_xor(ss, 2);
    float nrm = sqrtf(ss);
    nrm = nrm > 1e-12f ? nrm : 1e-12f;
    float rinv = 1.f / nrm;
    vA.x *= rinv; vA.y *= rinv; vA.z *= rinv; vA.w *= rinv;
    vB.x *= rinv; vB.y *= rinv; vB.z *= rinv; vB.w *= rinv;
    vA.x = vA.x > 0.f ? vA.x : 0.f;
    vA.y = vA.y > 0.f ? vA.y : 0.f;
    vA.z = vA.z > 0.f ? vA.z : 0.f;
    vA.w = vA.w > 0.f ? vA.w : 0.f;
    vB.x = vB.x > 0.f ? vB.x : 0.f;
    vB.y = vB.y > 0.f ? vB.y : 0.f;
    vB.z = vB.z > 0.f ? vB.z : 0.f;
    vB.w = vB.w > 0.f ? vB.w : 0.f;
    if (eh == 0) {
        float* hs = &sH[g * 36 + 8 * sc];
        hs[0] = vA.x; hs[1] = vA.y; hs[2] = vA.z; hs[3] = vA.w;
        hs[4] = vB.x; hs[5] = vB.y; hs[6] = vB.z; hs[7] = vB.w;
    }
    __syncthreads();
    int c = tid & 31;
    float a2f = bp[c];
#pragma unroll
    for (int k = 0; k < HH; ++k) a2f += sH[g * 36 + k] * sWpT[k * 36 + c];
    float s2 = a2f * a2f;
    s2 += __shfl_xor(s2, 1);
    s2 += __shfl_xor(s2, 2);
    s2 += __shfl_xor(s2, 4);
    s2 += __shfl_xor(s2, 8);
    s2 += __shfl_xor(s2, 16);
    float nrm2 = sqrtf(s2);
    nrm2 = nrm2 > 1e-12f ? nrm2 : 1e-12f;
    out[(size_t)n * HH + c] = a2f / nrm2;
}

__global__ void p4_k(const int* __restrict__ csrU, const int* __restrict__ rsU,
                     const __half* __restrict__ Si2, const float* __restrict__ Ru,
                     const float* __restrict__ b1_iu,
                     const float* __restrict__ wp_user, const float* __restrict__ bp_user,
                     const int* __restrict__ csrI, const int* __restrict__ rsI,
                     const __half* __restrict__ Su2, const float* __restrict__ Ri,
                     const float* __restrict__ b1_ui,
                     const float* __restrict__ wp_item, const float* __restrict__ bp_item,
                     float* __restrict__ out) {
    __shared__ float smem[HH * 36 + 8 * 36];
    int b = blockIdx.x;
    if (b < G_P0U) {
        pull1f_body(csrU, rsU, Si2, Ru, b1_iu, wp_user, bp_user, out, b, smem);
    } else {
        pull1f_body(csrI, rsI, Su2, Ri, b1_ui, wp_item, bp_item,
                    out + (size_t)NU * HH, b - G_P0U, smem);
    }
}

// ================= host =================

extern "C" void kernel_launch(void* const* d_in, const int* in_sizes, int n_in,
                              void* d_out, int out_size, void* d_ws, size_t ws_size,
                              hipStream_t stream) {
    const float* x_user = (const float*)d_in[0];
    const float* x_item = (const float*)d_in[1];
    const int* eu = (const int*)d_in[2];
    const int* ei = (const int*)d_in[3];
    const float* wl0_ui = (const float*)d_in[4];
    const float* b0_ui  = (const float*)d_in[5];
    const float* wr0_ui = (const float*)d_in[6];
    const float* wl0_iu = (const float*)d_in[7];
    const float* b0_iu  = (const float*)d_in[8];
    const float* wr0_iu = (const float*)d_in[9];
    const float* wl1_ui = (const float*)d_in[10];
    const float* b1_ui  = (const float*)d_in[11];
    const float* wr1_ui = (const float*)d_in[12];
    const float* wl1_iu = (const float*)d_in[13];
    const float* b1_iu  = (const float*)d_in[14];
    const float* wr1_iu = (const float*)d_in[15];
    const float* wp_user = (const float*)d_in[16];
    const float* bp_user = (const float*)d_in[17];
    const float* wp_item = (const float*)d_in[18];
    const float* bp_item = (const float*)d_in[19];
    float* out = (float*)d_out;
    (void)in_sizes; (void)n_in; (void)out_size; (void)ws_size;

    char* base = (char*)d_ws;
    size_t off = 0;
    auto take = [&](size_t bytes) -> size_t {
        size_t o = off;
        off += (bytes + 255) & ~(size_t)255;
        return o;
    };
    size_t o_rsU  = take((size_t)(NU + 1) * 4);
    size_t o_rsI  = take((size_t)(NI + 1) * 4);
    size_t o_cntU = take((size_t)NBU * NCH * 4);
    size_t o_cntI = take((size_t)NBI * NCH * 4);
    size_t o_csrU = take((size_t)NE * 4);
    size_t o_csrI = take((size_t)NE * 4);
    size_t o_partU = take((size_t)NE * 8);
    size_t o_partI = take((size_t)NE * 8);
    size_t o_Su = take((size_t)NU * HH * 2);   // fp16 message tables
    size_t o_Si = take((size_t)NI * HH * 2);
    size_t o_Su2 = take((size_t)NU * HH * 2);
    size_t o_Si2 = take((size_t)NI * HH * 2);
    size_t o_Ru = take((size_t)NU * HH * 4);   // f32 self tables
    size_t o_Ri = take((size_t)NI * HH * 4);

    int* rsU  = (int*)(base + o_rsU);
    int* rsI  = (int*)(base + o_rsI);
    int* cntU = (int*)(base + o_cntU);
    int* cntI = (int*)(base + o_cntI);
    int* csrU = (int*)(base + o_csrU);
    int* csrI = (int*)(base + o_csrI);
    int2* partU = (int2*)(base + o_partU);
    int2* partI = (int2*)(base + o_partI);
    __half* Su = (__half*)(base + o_Su);
    __half* Si = (__half*)(base + o_Si);
    __half* Su2 = (__half*)(base + o_Su2);
    __half* Si2 = (__half*)(base + o_Si2);
    float* Ru = (float*)(base + o_Ru);
    float* Ri = (float*)(base + o_Ri);

    // ---- radix CSR build (no global random atomics, no memset) ----
    cnt1_k<<<2 * NCH, 256, 0, stream>>>((const int4*)eu, (const int4*)ei, cntU, cntI);
    scan2_k<<<1, 1024, 0, stream>>>(cntU, NBU * NCH, cntI, NBI * NCH);
    part_k<<<2 * NCH, 256, 0, stream>>>((const int4*)eu, (const int4*)ei,
                                        cntU, cntI, partU, partI);
    build_k<<<NBU + NBI, 1024, 0, stream>>>(partU, partI, cntU, cntI,
                                            rsU, rsI, csrU, csrI);

    // ---- layer-0 projections via MFMA (f16 inputs, f32 accum) ----
    p1m_k<<<GPU_B + GPI_B, 256, 0, stream>>>(x_user, x_item, wl0_ui, wr0_iu,
                                             wl0_iu, wr0_ui, Su, Ru, Si, Ri);

    // ---- layer-0 pulls fused with layer-1 projections ----
    p23_k<<<G_P0I + G_P0U, 256, 0, stream>>>(csrI, rsI, Su, Ri, b0_ui, wl1_iu, wr1_ui, Si2,
                                             csrU, rsU, Si, Ru, b0_iu, wl1_ui, wr1_iu, Su2);

    // ---- layer-1 pulls + final projections -> out ----
    p4_k<<<G_P0U + G_P0I, 256, 0, stream>>>(csrU, rsU, Si2, Ru, b1_iu, wp_user, bp_user,
                                            csrI, rsI, Su2, Ri, b1_ui, wp_item, bp_item,
                                            out);
}